// Round 1
// 1165.386 us; speedup vs baseline: 1.2874x; 1.2874x over previous
//
#include <hip/hip_runtime.h>
#include <stdint.h>

// ---------------------------------------------------------------------------
// ActorCriticRNN on MI355X.
//   prep:  weights -> bf16 (B^T layout), Wh -> MFMA-fragment-linear.
//   G1:    emb = relu(obs @ W_emb + b_emb)             bf16 MFMA
//   G2:    gi  = emb @ Wi + bi (hoisted out of scan)   bf16 MFMA
//   GRU:   chunk-parallel: dones (p=0.5) reset h, so chunks of 32 steps
//          speculated with carry=0 are correct from each row's first done.
//          Main: 256 WGs (16 batch-tiles x 16 chunks). Fixup now PARALLEL:
//          240 WGs = (chunk 1..15) x (16 batch-tiles); carry-in for chunk c
//          is speculative hend[c-1], exact whenever the row saw >=1 done in
//          chunk c-1 (prob of violation 2^-32/row/chunk). A violation sets a
//          flag; sequential fallback k_gru_fix re-runs only then.
//   G3:    [a|c] = relu(y @ [W_a|W_c1] + b)            bf16 MFMA
//   G4:    logits masked by avail; G5: critic dot; out0: hidden = y[T-1].
// ---------------------------------------------------------------------------

typedef short short8 __attribute__((ext_vector_type(8)));
typedef float f32x4  __attribute__((ext_vector_type(4)));

#define T_DIM 512
#define CHUNK 32
#define NCH   16

// output offsets (fp32 elements)
#define OUT_HID  ((size_t)0)
#define OUT_LC1  ((size_t)65536)
#define OUT_LC2  ((size_t)4259840)
#define OUT_MC   ((size_t)8454144)
#define OUT_HINT ((size_t)10551296)
#define OUT_CRIT ((size_t)18939904)

__device__ __forceinline__ unsigned short f2bf(float f) {
    unsigned u = __float_as_uint(f);
    u += 0x7fffu + ((u >> 16) & 1u);          // round-to-nearest-even
    return (unsigned short)(u >> 16);
}
__device__ __forceinline__ float bf2f(unsigned short h) {
    return __uint_as_float(((unsigned)h) << 16);
}

__device__ __forceinline__ unsigned short gru_cell(
    float ir, float iz, float inn, float ho,
    float hrv, float hzv, float hnv, float bh)
{
    float rg = 1.f / (1.f + __expf(-(ir + hrv)));
    float z  = 1.f / (1.f + __expf(-(iz + hzv)));
    float ex = __expf(2.f * (inn + rg * (hnv + bh)));
    float n  = 1.f - 2.f / (ex + 1.f);        // tanh, inf-safe
    return f2bf((1.f - z) * n + z * ho);
}

// ---------------------------------------------------------------------------
// prep (R1-verified; + zero the fixup-fallback flag)
// ---------------------------------------------------------------------------
__global__ __launch_bounds__(256, 4) void k_prep(
    const float* __restrict__ W_emb, const float* __restrict__ Wi,
    const float* __restrict__ Wh,    const float* __restrict__ W_a,
    const float* __restrict__ W_c1,  const float* __restrict__ W_lc1,
    const float* __restrict__ W_lc2, const float* __restrict__ W_mc,
    const float* __restrict__ W_hint,
    const float* __restrict__ b_lc1, const float* __restrict__ b_lc2,
    const float* __restrict__ b_mc,  const float* __restrict__ b_hint,
    unsigned short* __restrict__ WembT, unsigned short* __restrict__ WiT,
    unsigned short* __restrict__ WhF,   unsigned short* __restrict__ WacT,
    unsigned short* __restrict__ WlogT, float* __restrict__ blog,
    int* __restrict__ fixflag)
{
    int i = blockIdx.x * 256 + threadIdx.x;
    if (i < 131072) {                         // WembT[n][k] = W_emb[k][n]
        int n = i >> 9, k = i & 511;
        WembT[i] = f2bf(W_emb[k * 256 + n]);
        return;
    }
    i -= 131072;
    if (i < 196608) {                         // WiT[n][k] = Wi[k][n]
        int n = i >> 8, k = i & 255;
        WiT[i] = f2bf(Wi[k * 768 + n]);
        return;
    }
    i -= 196608;
    if (i < 196608) {                         // Wh fragment-linear
        int jj = i & 7, L = (i >> 3) & 63, ks = (i >> 9) & 7, rest = i >> 12;
        int w = rest / 6, i6 = rest % 6, rho = i6 >> 1, s = i6 & 1;
        int k   = ks * 32 + ((L >> 4) << 3) + jj;
        int col = rho * 256 + w * 32 + s * 16 + (L & 15);
        WhF[i] = f2bf(Wh[k * 768 + col]);
        return;
    }
    i -= 196608;
    if (i < 131072) {                         // WacT
        int n = i >> 8, k = i & 255;
        WacT[i] = f2bf(n < 256 ? W_a[k * 256 + n] : W_c1[k * 256 + (n - 256)]);
        return;
    }
    i -= 131072;
    if (i < 40960) {                          // WlogT (N padded to 160)
        int n = i >> 8, k = i & 255;
        float v;
        if      (n < 32)  v = W_lc1[k * 32 + n];
        else if (n < 64)  v = W_lc2[k * 32 + (n - 32)];
        else if (n < 80)  v = W_mc [k * 16 + (n - 64)];
        else if (n < 144) v = W_hint[k * 64 + (n - 80)];
        else              v = 0.f;
        WlogT[i] = f2bf(v);
        return;
    }
    i -= 40960;
    if (i < 160) {
        float v;
        if      (i < 32)  v = b_lc1[i];
        else if (i < 64)  v = b_lc2[i - 32];
        else if (i < 80)  v = b_mc [i - 64];
        else if (i < 144) v = b_hint[i - 80];
        else              v = 0.f;
        blog[i] = v;
        return;
    }
    i -= 160;
    if (i == 0) *fixflag = 0;
}

// ---------------------------------------------------------------------------
// G1: emb = relu(obs @ W_emb + b_emb)  (unchanged)
// ---------------------------------------------------------------------------
__global__ __launch_bounds__(256, 3) void k_gemm_obs(
    const float* __restrict__ A, const unsigned short* __restrict__ Bt,
    const float* __restrict__ bias, unsigned short* __restrict__ out)
{
    __shared__ unsigned short As[128][72];
    __shared__ unsigned short Bs[128][72];
    const int tid = threadIdx.x, w = tid >> 6, L = tid & 63;
    const int mq = (w >> 1) * 64, nq = (w & 1) * 64;
    const int m0 = blockIdx.x * 128, n0 = blockIdx.y * 128;
    const int sr = tid >> 1, sh = (tid & 1) * 32;
    const int lc = L & 15, lq8 = (L >> 4) * 8, lr = (L >> 4) * 4;

    f32x4 acc[4][4];
#pragma unroll
    for (int i = 0; i < 4; i++)
#pragma unroll
        for (int j = 0; j < 4; j++) acc[i][j] = 0;

    const float* Ag = A + (size_t)(m0 + sr) * 512 + sh;
    const unsigned short* Bg = Bt + (size_t)(n0 + sr) * 512 + sh;

    for (int kt = 0; kt < 512; kt += 64) {
#pragma unroll
        for (int c = 0; c < 32; c += 8) {
            f32x4 v0 = *(const f32x4*)(Ag + kt + c);
            f32x4 v1 = *(const f32x4*)(Ag + kt + c + 4);
            short8 pk;
            pk[0] = (short)f2bf(v0[0]); pk[1] = (short)f2bf(v0[1]);
            pk[2] = (short)f2bf(v0[2]); pk[3] = (short)f2bf(v0[3]);
            pk[4] = (short)f2bf(v1[0]); pk[5] = (short)f2bf(v1[1]);
            pk[6] = (short)f2bf(v1[2]); pk[7] = (short)f2bf(v1[3]);
            *(short8*)&As[sr][sh + c] = pk;
            *(short8*)&Bs[sr][sh + c] = *(const short8*)(Bg + kt + c);
        }
        __syncthreads();
#pragma unroll
        for (int ks = 0; ks < 2; ks++) {
            short8 a[4], b[4];
#pragma unroll
            for (int i = 0; i < 4; i++)
                a[i] = *(const short8*)&As[mq + i * 16 + lc][ks * 32 + lq8];
#pragma unroll
            for (int j = 0; j < 4; j++)
                b[j] = *(const short8*)&Bs[nq + j * 16 + lc][ks * 32 + lq8];
#pragma unroll
            for (int i = 0; i < 4; i++)
#pragma unroll
                for (int j = 0; j < 4; j++)
                    acc[i][j] = __builtin_amdgcn_mfma_f32_16x16x32_bf16(a[i], b[j], acc[i][j], 0, 0, 0);
        }
        __syncthreads();
    }
#pragma unroll
    for (int i = 0; i < 4; i++)
#pragma unroll
        for (int j = 0; j < 4; j++) {
            int col = n0 + nq + j * 16 + lc;
            float bv = bias[col];
#pragma unroll
            for (int rg = 0; rg < 4; rg++) {
                int row = m0 + mq + i * 16 + lr + rg;
                float v = acc[i][j][rg] + bv;
                v = fmaxf(v, 0.f);
                out[(size_t)row * 256 + col] = f2bf(v);
            }
        }
}

// ---------------------------------------------------------------------------
// Generic bf16-A GEMM, K=256  (unchanged)
// ---------------------------------------------------------------------------
__global__ __launch_bounds__(256, 3) void k_gemm_bf(
    const unsigned short* __restrict__ A, const unsigned short* __restrict__ Bt,
    const float* __restrict__ biasA, const float* __restrict__ biasB,
    int nsplit, int relu, int N, unsigned short* __restrict__ out)
{
    __shared__ unsigned short As[128][72];
    __shared__ unsigned short Bs[128][72];
    const int tid = threadIdx.x, w = tid >> 6, L = tid & 63;
    const int mq = (w >> 1) * 64, nq = (w & 1) * 64;
    const int m0 = blockIdx.x * 128, n0 = blockIdx.y * 128;
    const int sr = tid >> 1, sh = (tid & 1) * 32;
    const int lc = L & 15, lq8 = (L >> 4) * 8, lr = (L >> 4) * 4;

    f32x4 acc[4][4];
#pragma unroll
    for (int i = 0; i < 4; i++)
#pragma unroll
        for (int j = 0; j < 4; j++) acc[i][j] = 0;

    const unsigned short* Ag = A + (size_t)(m0 + sr) * 256 + sh;
    const unsigned short* Bg = Bt + (size_t)(n0 + sr) * 256 + sh;

    for (int kt = 0; kt < 256; kt += 64) {
#pragma unroll
        for (int c = 0; c < 32; c += 8) {
            *(short8*)&As[sr][sh + c] = *(const short8*)(Ag + kt + c);
            *(short8*)&Bs[sr][sh + c] = *(const short8*)(Bg + kt + c);
        }
        __syncthreads();
#pragma unroll
        for (int ks = 0; ks < 2; ks++) {
            short8 a[4], b[4];
#pragma unroll
            for (int i = 0; i < 4; i++)
                a[i] = *(const short8*)&As[mq + i * 16 + lc][ks * 32 + lq8];
#pragma unroll
            for (int j = 0; j < 4; j++)
                b[j] = *(const short8*)&Bs[nq + j * 16 + lc][ks * 32 + lq8];
#pragma unroll
            for (int i = 0; i < 4; i++)
#pragma unroll
                for (int j = 0; j < 4; j++)
                    acc[i][j] = __builtin_amdgcn_mfma_f32_16x16x32_bf16(a[i], b[j], acc[i][j], 0, 0, 0);
        }
        __syncthreads();
    }
#pragma unroll
    for (int i = 0; i < 4; i++)
#pragma unroll
        for (int j = 0; j < 4; j++) {
            int col = n0 + nq + j * 16 + lc;
            float bv = (col < nsplit) ? biasA[col] : biasB[col - nsplit];
#pragma unroll
            for (int rg = 0; rg < 4; rg++) {
                int row = m0 + mq + i * 16 + lr + rg;
                float v = acc[i][j][rg] + bv;
                if (relu) v = fmaxf(v, 0.f);
                out[(size_t)row * N + col] = f2bf(v);
            }
        }
}

// ---------------------------------------------------------------------------
// GRU main pass: 256 WGs = (batch-tile g = x&15) x (chunk c = x>>4).
// Speculates carry-in = 0 for c>0 (chunk 0 uses true h0). Stores h_end[c].
// ---------------------------------------------------------------------------
__global__ __launch_bounds__(512, 1) void k_gru_main(
    const unsigned short* __restrict__ gi, const unsigned short* __restrict__ WhF,
    const int* __restrict__ dones, const float* __restrict__ h0,
    const float* __restrict__ bhn, unsigned short* __restrict__ y,
    unsigned short* __restrict__ hend)
{
    __shared__ unsigned short hT[2][16][264];
    __shared__ unsigned int rowbits[16];      // bit t' of dones for each row
    const int tid = threadIdx.x, w = tid >> 6, L = tid & 63;
    const int g = blockIdx.x & 15, c = blockIdx.x >> 4;
    const int b0 = g * 16, t0 = c * CHUNK;
    const int rowg = L >> 4, lc = L & 15;

    short8 Bf[6][8];
#pragma unroll
    for (int i6 = 0; i6 < 6; i6++)
#pragma unroll
        for (int ks = 0; ks < 8; ks++)
            Bf[i6][ks] = *(const short8*)(WhF + ((((size_t)w * 6 + i6) * 8 + ks) * 64 + L) * 8);

    const float bh0 = bhn[w * 32 + lc], bh1 = bhn[w * 32 + 16 + lc];

    // build dones bitmask for this chunk
    if (tid < 16) rowbits[tid] = 0;
    __syncthreads();
    {
        int tp = tid >> 4, r = tid & 15;
        if (dones[(t0 + tp) * 256 + b0 + r]) atomicOr(&rowbits[r], 1u << tp);
    }
    __syncthreads();

    unsigned rbr[4];
#pragma unroll
    for (int r = 0; r < 4; r++) rbr[r] = rowbits[rowg * 4 + r];

    // init h: c==0 -> h0 with done[0] reset; c>0 -> speculative 0
    {
        int hrow = tid >> 5, hcol = (tid & 31) * 8;
        bool rz = (rowbits[hrow] & 1u) != 0;
#pragma unroll
        for (int cc = 0; cc < 8; cc++) {
            unsigned short v = 0;
            if (c == 0 && !rz) v = f2bf(h0[(b0 + hrow) * 256 + hcol + cc]);
            hT[0][hrow][hcol + cc] = v;
        }
    }
    __syncthreads();

#pragma unroll 2
    for (int tp = 0; tp < CHUNK; tp++) {
        const int cur = tp & 1, nxt = cur ^ 1;
        const int t = t0 + tp;

        f32x4 acc0 = 0, acc1 = 0, acc2 = 0, acc3 = 0, acc4 = 0, acc5 = 0;
#pragma unroll
        for (int ks = 0; ks < 8; ks++) {
            short8 a = *(const short8*)&hT[cur][lc][ks * 32 + rowg * 8];
            acc0 = __builtin_amdgcn_mfma_f32_16x16x32_bf16(a, Bf[0][ks], acc0, 0, 0, 0);
            acc1 = __builtin_amdgcn_mfma_f32_16x16x32_bf16(a, Bf[1][ks], acc1, 0, 0, 0);
            acc2 = __builtin_amdgcn_mfma_f32_16x16x32_bf16(a, Bf[2][ks], acc2, 0, 0, 0);
            acc3 = __builtin_amdgcn_mfma_f32_16x16x32_bf16(a, Bf[3][ks], acc3, 0, 0, 0);
            acc4 = __builtin_amdgcn_mfma_f32_16x16x32_bf16(a, Bf[4][ks], acc4, 0, 0, 0);
            acc5 = __builtin_amdgcn_mfma_f32_16x16x32_bf16(a, Bf[5][ks], acc5, 0, 0, 0);
        }

        const unsigned short* gb = gi + (size_t)(t * 256 + b0) * 768;
        unsigned short* yb = y + (size_t)(t * 256 + b0) * 256;
#pragma unroll
        for (int s = 0; s < 2; s++) {
            const int j = w * 32 + s * 16 + lc;
            f32x4 hrv = s ? acc1 : acc0;
            f32x4 hzv = s ? acc3 : acc2;
            f32x4 hnv = s ? acc5 : acc4;
            float bh = s ? bh1 : bh0;
#pragma unroll
            for (int r = 0; r < 4; r++) {
                int row = rowg * 4 + r;
                float ir  = bf2f(gb[row * 768 + j]);
                float iz  = bf2f(gb[row * 768 + 256 + j]);
                float inn = bf2f(gb[row * 768 + 512 + j]);
                float ho  = bf2f(hT[cur][row][j]);
                unsigned short hb = gru_cell(ir, iz, inn, ho, hrv[r], hzv[r], hnv[r], bh);
                yb[row * 256 + j] = hb;
                if (tp < CHUNK - 1) {
                    hT[nxt][row][j] = ((rbr[r] >> (tp + 1)) & 1u) ? (unsigned short)0 : hb;
                } else {
                    hend[((size_t)c * 256 + b0 + row) * 256 + j] = hb;   // raw carry-out
                }
            }
        }
        __syncthreads();
    }
}

// ---------------------------------------------------------------------------
// PARALLEL GRU fixup: 240 WGs = (chunk c=1..15) x (16 batch-tiles).
// Carry-in for chunk c = speculative hend[c-1], which is EXACT for every row
// that saw >=1 done in chunk c-1 (speculation converges at the first done).
// A row with zero dones in a 32-step chunk (prob 2^-32) invalidates this;
// that raises *flag and the sequential fallback below redoes everything.
// Each WG recomputes only steps before each row's first done in chunk c.
// ---------------------------------------------------------------------------
__global__ __launch_bounds__(512, 1) void k_gru_fix_par(
    const unsigned short* __restrict__ gi, const unsigned short* __restrict__ WhF,
    const int* __restrict__ dones, const float* __restrict__ bhn,
    const unsigned short* __restrict__ hend, unsigned short* __restrict__ y,
    int* __restrict__ flag)
{
    __shared__ unsigned short hT[2][16][264];
    __shared__ unsigned int rowbits[16], prevbits[16];
    __shared__ int sh_fd[16];
    const int tid = threadIdx.x, w = tid >> 6, L = tid & 63;
    const int g = blockIdx.x & 15, c = (blockIdx.x >> 4) + 1;
    const int b0 = g * 16, t0 = c * CHUNK;
    const int rowg = L >> 4, lc = L & 15;
    const int hrow = tid >> 5, hcol = (tid & 31) * 8;

    // issue weight-fragment loads first (latency overlap with masks)
    short8 Bf[6][8];
#pragma unroll
    for (int i6 = 0; i6 < 6; i6++)
#pragma unroll
        for (int ks = 0; ks < 8; ks++)
            Bf[i6][ks] = *(const short8*)(WhF + ((((size_t)w * 6 + i6) * 8 + ks) * 64 + L) * 8);

    const float bh0 = bhn[w * 32 + lc], bh1 = bhn[w * 32 + 16 + lc];

    if (tid < 16) { rowbits[tid] = 0; prevbits[tid] = 0; }
    __syncthreads();
    {
        int tp = tid >> 4, r = tid & 15;
        if (dones[(t0 + tp) * 256 + b0 + r])         atomicOr(&rowbits[r],  1u << tp);
        if (dones[(t0 - CHUNK + tp) * 256 + b0 + r]) atomicOr(&prevbits[r], 1u << tp);
    }
    __syncthreads();
    if (tid < 16) {
        unsigned m = rowbits[tid];
        sh_fd[tid] = m ? __builtin_ctz(m) : CHUNK;
        if (prevbits[tid] == 0) atomicOr(flag, 1);   // carry-in untrusted
    }
    __syncthreads();

    int maxfix = 0;
    unsigned rbr[4]; int fdr[4];
#pragma unroll
    for (int r = 0; r < 16; r++) maxfix = max(maxfix, sh_fd[r]);
    if (maxfix == 0) return;                          // all rows reset at step 0
#pragma unroll
    for (int r = 0; r < 4; r++) {
        rbr[r] = rowbits[rowg * 4 + r];
        fdr[r] = sh_fd[rowg * 4 + r];
    }

    // carry-in: speculative end of chunk c-1, with chunk-c step-0 reset
    {
        short8 hv = *(const short8*)(hend + ((size_t)(c - 1) * 256 + b0 + hrow) * 256 + hcol);
        if (rowbits[hrow] & 1u) { short8 z = {0,0,0,0,0,0,0,0}; hv = z; }
        *(short8*)&hT[0][hrow][hcol] = hv;
    }
    __syncthreads();

    int cur = 0;
    for (int tp = 0; tp < maxfix; tp++) {
        const int nxt = cur ^ 1;
        const int t = t0 + tp;

        f32x4 acc0 = 0, acc1 = 0, acc2 = 0, acc3 = 0, acc4 = 0, acc5 = 0;
#pragma unroll
        for (int ks = 0; ks < 8; ks++) {
            short8 a = *(const short8*)&hT[cur][lc][ks * 32 + rowg * 8];
            acc0 = __builtin_amdgcn_mfma_f32_16x16x32_bf16(a, Bf[0][ks], acc0, 0, 0, 0);
            acc1 = __builtin_amdgcn_mfma_f32_16x16x32_bf16(a, Bf[1][ks], acc1, 0, 0, 0);
            acc2 = __builtin_amdgcn_mfma_f32_16x16x32_bf16(a, Bf[2][ks], acc2, 0, 0, 0);
            acc3 = __builtin_amdgcn_mfma_f32_16x16x32_bf16(a, Bf[3][ks], acc3, 0, 0, 0);
            acc4 = __builtin_amdgcn_mfma_f32_16x16x32_bf16(a, Bf[4][ks], acc4, 0, 0, 0);
            acc5 = __builtin_amdgcn_mfma_f32_16x16x32_bf16(a, Bf[5][ks], acc5, 0, 0, 0);
        }

        const unsigned short* gb = gi + (size_t)(t * 256 + b0) * 768;
        unsigned short* yb = y + (size_t)(t * 256 + b0) * 256;
#pragma unroll
        for (int s = 0; s < 2; s++) {
            const int j = w * 32 + s * 16 + lc;
            f32x4 hrv = s ? acc1 : acc0;
            f32x4 hzv = s ? acc3 : acc2;
            f32x4 hnv = s ? acc5 : acc4;
            float bh = s ? bh1 : bh0;
#pragma unroll
            for (int r = 0; r < 4; r++) {
                int row = rowg * 4 + r;
                float ir  = bf2f(gb[row * 768 + j]);
                float iz  = bf2f(gb[row * 768 + 256 + j]);
                float inn = bf2f(gb[row * 768 + 512 + j]);
                float ho  = bf2f(hT[cur][row][j]);
                unsigned short hb = gru_cell(ir, iz, inn, ho, hrv[r], hzv[r], hnv[r], bh);
                if (tp < fdr[r]) yb[row * 256 + j] = hb;   // only fix wrong prefix
                unsigned short hw = hb;
                if (tp + 1 < CHUNK && ((rbr[r] >> (tp + 1)) & 1u)) hw = 0;
                hT[nxt][row][j] = hw;
            }
        }
        __syncthreads();
        cur = nxt;
    }
}

// ---------------------------------------------------------------------------
// GRU fixup FALLBACK (sequential over chunks): only runs if flag was set by
// k_gru_fix_par, i.e. some row had a done-free 32-step chunk (prob ~2^-32).
// ---------------------------------------------------------------------------
__global__ __launch_bounds__(512, 1) void k_gru_fix(
    const unsigned short* __restrict__ gi, const unsigned short* __restrict__ WhF,
    const int* __restrict__ dones, const float* __restrict__ bhn,
    const unsigned short* __restrict__ hend, unsigned short* __restrict__ y,
    const int* __restrict__ flag)
{
    if (*flag == 0) return;                   // uniform: common case, exit fast

    __shared__ unsigned short hT[2][16][264];
    __shared__ unsigned int rowbits[16];
    __shared__ int sh_fd[16];
    const int tid = threadIdx.x, w = tid >> 6, L = tid & 63;
    const int b0 = blockIdx.x * 16;
    const int rowg = L >> 4, lc = L & 15;
    const int hrow = tid >> 5, hcol = (tid & 31) * 8;

    short8 Bf[6][8];
#pragma unroll
    for (int i6 = 0; i6 < 6; i6++)
#pragma unroll
        for (int ks = 0; ks < 8; ks++)
            Bf[i6][ks] = *(const short8*)(WhF + ((((size_t)w * 6 + i6) * 8 + ks) * 64 + L) * 8);

    const float bh0 = bhn[w * 32 + lc], bh1 = bhn[w * 32 + 16 + lc];

    // carry = corrected end of chunk 0 (chunk 0 speculation used true h0)
    *(short8*)&hT[0][hrow][hcol] =
        *(const short8*)(hend + (size_t)(b0 + hrow) * 256 + hcol);
    int cur = 0;

    for (int c = 1; c < NCH; c++) {
        const int t0 = c * CHUNK;
        if (tid < 16) rowbits[tid] = 0;
        __syncthreads();
        {
            int tp = tid >> 4, r = tid & 15;
            if (dones[(t0 + tp) * 256 + b0 + r]) atomicOr(&rowbits[r], 1u << tp);
        }
        __syncthreads();
        if (tid < 16) {
            unsigned m = rowbits[tid];
            sh_fd[tid] = m ? __builtin_ctz(m) : CHUNK;
        }
        __syncthreads();

        int maxfix = 0;
        unsigned rbr[4]; int fdr[4];
#pragma unroll
        for (int r = 0; r < 16; r++) maxfix = max(maxfix, sh_fd[r]);
#pragma unroll
        for (int r = 0; r < 4; r++) {
            rbr[r] = rowbits[rowg * 4 + r];
            fdr[r] = sh_fd[rowg * 4 + r];
        }
        // apply this chunk's step-0 reset to the carry
        if (rowbits[hrow] & 1u) {
#pragma unroll
            for (int cc = 0; cc < 8; cc++) hT[cur][hrow][hcol + cc] = 0;
        }
        __syncthreads();

        for (int tp = 0; tp < maxfix; tp++) {
            const int nxt = cur ^ 1;
            const int t = t0 + tp;

            f32x4 acc0 = 0, acc1 = 0, acc2 = 0, acc3 = 0, acc4 = 0, acc5 = 0;
#pragma unroll
            for (int ks = 0; ks < 8; ks++) {
                short8 a = *(const short8*)&hT[cur][lc][ks * 32 + rowg * 8];
                acc0 = __builtin_amdgcn_mfma_f32_16x16x32_bf16(a, Bf[0][ks], acc0, 0, 0, 0);
                acc1 = __builtin_amdgcn_mfma_f32_16x16x32_bf16(a, Bf[1][ks], acc1, 0, 0, 0);
                acc2 = __builtin_amdgcn_mfma_f32_16x16x32_bf16(a, Bf[2][ks], acc2, 0, 0, 0);
                acc3 = __builtin_amdgcn_mfma_f32_16x16x32_bf16(a, Bf[3][ks], acc3, 0, 0, 0);
                acc4 = __builtin_amdgcn_mfma_f32_16x16x32_bf16(a, Bf[4][ks], acc4, 0, 0, 0);
                acc5 = __builtin_amdgcn_mfma_f32_16x16x32_bf16(a, Bf[5][ks], acc5, 0, 0, 0);
            }

            const unsigned short* gb = gi + (size_t)(t * 256 + b0) * 768;
            unsigned short* yb = y + (size_t)(t * 256 + b0) * 256;
#pragma unroll
            for (int s = 0; s < 2; s++) {
                const int j = w * 32 + s * 16 + lc;
                f32x4 hrv = s ? acc1 : acc0;
                f32x4 hzv = s ? acc3 : acc2;
                f32x4 hnv = s ? acc5 : acc4;
                float bh = s ? bh1 : bh0;
#pragma unroll
                for (int r = 0; r < 4; r++) {
                    int row = rowg * 4 + r;
                    float ir  = bf2f(gb[row * 768 + j]);
                    float iz  = bf2f(gb[row * 768 + 256 + j]);
                    float inn = bf2f(gb[row * 768 + 512 + j]);
                    float ho  = bf2f(hT[cur][row][j]);
                    unsigned short hb = gru_cell(ir, iz, inn, ho, hrv[r], hzv[r], hnv[r], bh);
                    if (tp < fdr[r]) yb[row * 256 + j] = hb;   // only fix wrong prefix
                    unsigned short hw = hb;
                    if (tp + 1 < CHUNK && ((rbr[r] >> (tp + 1)) & 1u)) hw = 0;
                    hT[nxt][row][j] = hw;
                }
            }
            __syncthreads();
            cur = nxt;
        }

        // splice: rows that saw a done have correct speculative h_end
        if (sh_fd[hrow] < CHUNK) {
            *(short8*)&hT[cur][hrow][hcol] =
                *(const short8*)(hend + ((size_t)c * 256 + b0 + hrow) * 256 + hcol);
        }
        __syncthreads();
    }
}

// ---------------------------------------------------------------------------
// G4: logits (unchanged)
// ---------------------------------------------------------------------------
__global__ __launch_bounds__(256, 2) void k_logits(
    const unsigned short* __restrict__ ac, const unsigned short* __restrict__ Bt,
    const float* __restrict__ blog,
    const int* __restrict__ av1, const int* __restrict__ av2,
    const int* __restrict__ av3, const int* __restrict__ av4,
    float* __restrict__ outp)
{
    __shared__ unsigned short As[128][72];
    __shared__ unsigned short Bs[160][72];
    const int tid = threadIdx.x, w = tid >> 6, L = tid & 63;
    const int m0 = blockIdx.x * 128;
    const int sr = tid >> 1, sh = (tid & 1) * 32;
    const int lc = L & 15, lq8 = (L >> 4) * 8, lr = (L >> 4) * 4;

    f32x4 acc[2][10];
#pragma unroll
    for (int i = 0; i < 2; i++)
#pragma unroll
        for (int j = 0; j < 10; j++) acc[i][j] = 0;

    const unsigned short* Ag = ac + (size_t)(m0 + sr) * 512 + sh;

    for (int kt = 0; kt < 256; kt += 64) {
#pragma unroll
        for (int c = 0; c < 32; c += 8)
            *(short8*)&As[sr][sh + c] = *(const short8*)(Ag + kt + c);
        for (int u = tid; u < 320; u += 256) {
            int br = u >> 1, bh2 = (u & 1) * 32;
#pragma unroll
            for (int c = 0; c < 32; c += 8)
                *(short8*)&Bs[br][bh2 + c] = *(const short8*)(Bt + (size_t)br * 256 + kt + bh2 + c);
        }
        __syncthreads();
#pragma unroll
        for (int ks = 0; ks < 2; ks++) {
            short8 a[2], b[10];
#pragma unroll
            for (int i = 0; i < 2; i++)
                a[i] = *(const short8*)&As[w * 32 + i * 16 + lc][ks * 32 + lq8];
#pragma unroll
            for (int j = 0; j < 10; j++)
                b[j] = *(const short8*)&Bs[j * 16 + lc][ks * 32 + lq8];
#pragma unroll
            for (int i = 0; i < 2; i++)
#pragma unroll
                for (int j = 0; j < 10; j++)
                    acc[i][j] = __builtin_amdgcn_mfma_f32_16x16x32_bf16(a[i], b[j], acc[i][j], 0, 0, 0);
        }
        __syncthreads();
    }
#pragma unroll
    for (int j = 0; j < 10; j++) {
        int col = j * 16 + lc;
        if (col >= 144) continue;
        int gbase, adim; const int* av; size_t obase;
        if      (col < 32) { gbase = 0;  adim = 32; av = av1; obase = OUT_LC1; }
        else if (col < 64) { gbase = 32; adim = 32; av = av2; obase = OUT_LC2; }
        else if (col < 80) { gbase = 64; adim = 16; av = av3; obase = OUT_MC;  }
        else               { gbase = 80; adim = 64; av = av4; obase = OUT_HINT;}
        int cof = col - gbase;
        float bv = blog[col];
#pragma unroll
        for (int i = 0; i < 2; i++)
#pragma unroll
            for (int rg = 0; rg < 4; rg++) {
                int R = m0 + w * 32 + i * 16 + lr + rg;
                float v = acc[i][j][rg] + bv;
                int a_ = av[(size_t)R * adim + cof];
                v -= (1.f - (float)a_) * 1e10f;
                outp[obase + (size_t)R * adim + cof] = v;
            }
    }
}

// ---------------------------------------------------------------------------
// G5: critic (unchanged)
// ---------------------------------------------------------------------------
__global__ __launch_bounds__(256, 4) void k_critic(
    const unsigned short* __restrict__ ac, const float* __restrict__ W_c2,
    const float* __restrict__ b_c2, float* __restrict__ outp)
{
    const int tid = threadIdx.x, w = tid >> 6, L = tid & 63;
    f32x4 wv = *(const f32x4*)(W_c2 + L * 4);
    float bb = b_c2[0];
    int base = blockIdx.x * 64 + w * 16;
    for (int rr = 0; rr < 16; rr++) {
        int R = base + rr;
        const unsigned short* p = ac + (size_t)R * 512 + 256 + L * 4;
        float s = bf2f(p[0]) * wv[0] + bf2f(p[1]) * wv[1] +
                  bf2f(p[2]) * wv[2] + bf2f(p[3]) * wv[3];
#pragma unroll
        for (int o = 32; o > 0; o >>= 1) s += __shfl_down(s, o);
        if (L == 0) outp[OUT_CRIT + R] = s + bb;
    }
}

__global__ __launch_bounds__(256, 4) void k_hidden(
    const unsigned short* __restrict__ y, float* __restrict__ outp)
{
    int i = blockIdx.x * 256 + threadIdx.x;
    outp[OUT_HID + i] = bf2f(y[(size_t)511 * 65536 + i]);
}

// ---------------------------------------------------------------------------
extern "C" void kernel_launch(void* const* d_in, const int* in_sizes, int n_in,
                              void* d_out, int out_size, void* d_ws, size_t ws_size,
                              hipStream_t stream)
{
    const float* hidden = (const float*)d_in[0];
    const float* obs    = (const float*)d_in[1];
    const int*   dones  = (const int*)d_in[2];
    const int*   av1    = (const int*)d_in[3];
    const int*   av2    = (const int*)d_in[4];
    const int*   av3    = (const int*)d_in[5];
    const int*   av4    = (const int*)d_in[6];
    const float* W_emb  = (const float*)d_in[7];
    const float* b_emb  = (const float*)d_in[8];
    const float* Wi     = (const float*)d_in[9];
    const float* bi     = (const float*)d_in[10];
    const float* Wh     = (const float*)d_in[11];
    const float* bhn    = (const float*)d_in[12];
    const float* W_a    = (const float*)d_in[13];
    const float* b_a    = (const float*)d_in[14];
    const float* W_lc1  = (const float*)d_in[15];
    const float* b_lc1  = (const float*)d_in[16];
    const float* W_lc2  = (const float*)d_in[17];
    const float* b_lc2  = (const float*)d_in[18];
    const float* W_mc   = (const float*)d_in[19];
    const float* b_mc   = (const float*)d_in[20];
    const float* W_hint = (const float*)d_in[21];
    const float* b_hint = (const float*)d_in[22];
    const float* W_c1   = (const float*)d_in[23];
    const float* b_c1   = (const float*)d_in[24];
    const float* W_c2   = (const float*)d_in[25];
    const float* b_c2   = (const float*)d_in[26];

    char* ws = (char*)d_ws;
    unsigned short* WembT = (unsigned short*)(ws + 0);
    unsigned short* WiT   = (unsigned short*)(ws + 262144);
    unsigned short* WhF   = (unsigned short*)(ws + 655360);
    unsigned short* WacT  = (unsigned short*)(ws + 1048576);
    unsigned short* WlogT = (unsigned short*)(ws + 1310720);
    float*          blog  = (float*)(ws + 1392640);
    int*            fflag = (int*)(ws + 1393280);
    // emb (TB x 256 bf16, 67 MB) / hend (2 MB) / ac (TB x 512 bf16, 134 MB)
    // share a region: emb dies after G2; hend lives only gru_main->gru_fix;
    // ac written by G3 after fixup.
    unsigned short* emb   = (unsigned short*)(ws + 1393664);
    unsigned short* hend  = emb;
    unsigned short* ac    = emb;
    unsigned short* gibuf = (unsigned short*)(ws + 135611392);
    unsigned short* ybuf  = (unsigned short*)(ws + 336937984);
    float* outp = (float*)d_out;

    k_prep<<<2721, 256, 0, stream>>>(W_emb, Wi, Wh, W_a, W_c1, W_lc1, W_lc2,
                                     W_mc, W_hint, b_lc1, b_lc2, b_mc, b_hint,
                                     WembT, WiT, WhF, WacT, WlogT, blog, fflag);
    k_gemm_obs<<<dim3(1024, 2), 256, 0, stream>>>(obs, WembT, b_emb, emb);
    k_gemm_bf<<<dim3(1024, 6), 256, 0, stream>>>(emb, WiT, bi, bi, 768, 0, 768, gibuf);
    k_gru_main<<<256, 512, 0, stream>>>(gibuf, WhF, dones, hidden, bhn, ybuf, hend);
    k_gru_fix_par<<<240, 512, 0, stream>>>(gibuf, WhF, dones, bhn, hend, ybuf, fflag);
    k_gru_fix<<<16, 512, 0, stream>>>(gibuf, WhF, dones, bhn, hend, ybuf, fflag);
    k_gemm_bf<<<dim3(1024, 4), 256, 0, stream>>>(ybuf, WacT, b_a, b_c1, 256, 1, 512, ac);
    k_logits<<<1024, 256, 0, stream>>>(ac, WlogT, blog, av1, av2, av3, av4, outp);
    k_critic<<<2048, 256, 0, stream>>>(ac, W_c2, b_c2, outp);
    k_hidden<<<2048 / 8, 256, 0, stream>>>(ybuf, outp);
}

// Round 2
// 1023.030 us; speedup vs baseline: 1.4666x; 1.1392x over previous
//
#include <hip/hip_runtime.h>
#include <stdint.h>

// ---------------------------------------------------------------------------
// ActorCriticRNN on MI355X.
//   prep:  weights -> bf16 (B^T layout), Wh -> MFMA-fragment-linear.
//   G1:    emb = relu(obs @ W_emb + b_emb)             bf16 MFMA
//   G2:    gi  = emb @ Wi + bi  -> PACKED gate-planes  bf16 MFMA
//          layout: plane[gate] + ((t*16+g)*512 + tid)*8 + (r*2+s)
//          so each GRU thread reads its step's 24 gi values as 3x short8.
//   GRU:   chunk-parallel speculation (dones p=0.5 reset h). Main: 256 WGs.
//          gi prefetched one step ahead; y staged in LDS, stored as 16B/lane
//          full-line writes (kills the 2.5x RMW write amplification).
//          Fixup parallel over 240 (chunk,tile) WGs + sequential fallback
//          guarded by a flag (prob ~2^-32 per row-chunk).
//   G3:    [a|c] = relu(y @ [W_a|W_c1] + b)            bf16 MFMA
//   G4:    logits masked by avail; G5: critic dot; out0: hidden = y[T-1].
// ---------------------------------------------------------------------------

typedef short short8 __attribute__((ext_vector_type(8)));
typedef float f32x4  __attribute__((ext_vector_type(4)));

#define T_DIM 512
#define CHUNK 32
#define NCH   16
#define GIPL  ((size_t)33554432)   // gi gate-plane size in shorts (8192*512*8)

// output offsets (fp32 elements)
#define OUT_HID  ((size_t)0)
#define OUT_LC1  ((size_t)65536)
#define OUT_LC2  ((size_t)4259840)
#define OUT_MC   ((size_t)8454144)
#define OUT_HINT ((size_t)10551296)
#define OUT_CRIT ((size_t)18939904)

__device__ __forceinline__ unsigned short f2bf(float f) {
    unsigned u = __float_as_uint(f);
    u += 0x7fffu + ((u >> 16) & 1u);          // round-to-nearest-even
    return (unsigned short)(u >> 16);
}
__device__ __forceinline__ float bf2f(unsigned short h) {
    return __uint_as_float(((unsigned)h) << 16);
}

__device__ __forceinline__ unsigned short gru_cell(
    float ir, float iz, float inn, float ho,
    float hrv, float hzv, float hnv, float bh)
{
    float rg = 1.f / (1.f + __expf(-(ir + hrv)));
    float z  = 1.f / (1.f + __expf(-(iz + hzv)));
    float ex = __expf(2.f * (inn + rg * (hnv + bh)));
    float n  = 1.f - 2.f / (ex + 1.f);        // tanh, inf-safe
    return f2bf((1.f - z) * n + z * ho);
}

// ---------------------------------------------------------------------------
// prep (R1-verified; + zero the fixup-fallback flag)
// ---------------------------------------------------------------------------
__global__ __launch_bounds__(256, 4) void k_prep(
    const float* __restrict__ W_emb, const float* __restrict__ Wi,
    const float* __restrict__ Wh,    const float* __restrict__ W_a,
    const float* __restrict__ W_c1,  const float* __restrict__ W_lc1,
    const float* __restrict__ W_lc2, const float* __restrict__ W_mc,
    const float* __restrict__ W_hint,
    const float* __restrict__ b_lc1, const float* __restrict__ b_lc2,
    const float* __restrict__ b_mc,  const float* __restrict__ b_hint,
    unsigned short* __restrict__ WembT, unsigned short* __restrict__ WiT,
    unsigned short* __restrict__ WhF,   unsigned short* __restrict__ WacT,
    unsigned short* __restrict__ WlogT, float* __restrict__ blog,
    int* __restrict__ fixflag)
{
    int i = blockIdx.x * 256 + threadIdx.x;
    if (i < 131072) {                         // WembT[n][k] = W_emb[k][n]
        int n = i >> 9, k = i & 511;
        WembT[i] = f2bf(W_emb[k * 256 + n]);
        return;
    }
    i -= 131072;
    if (i < 196608) {                         // WiT[n][k] = Wi[k][n]
        int n = i >> 8, k = i & 255;
        WiT[i] = f2bf(Wi[k * 768 + n]);
        return;
    }
    i -= 196608;
    if (i < 196608) {                         // Wh fragment-linear
        int jj = i & 7, L = (i >> 3) & 63, ks = (i >> 9) & 7, rest = i >> 12;
        int w = rest / 6, i6 = rest % 6, rho = i6 >> 1, s = i6 & 1;
        int k   = ks * 32 + ((L >> 4) << 3) + jj;
        int col = rho * 256 + w * 32 + s * 16 + (L & 15);
        WhF[i] = f2bf(Wh[k * 768 + col]);
        return;
    }
    i -= 196608;
    if (i < 131072) {                         // WacT
        int n = i >> 8, k = i & 255;
        WacT[i] = f2bf(n < 256 ? W_a[k * 256 + n] : W_c1[k * 256 + (n - 256)]);
        return;
    }
    i -= 131072;
    if (i < 40960) {                          // WlogT (N padded to 160)
        int n = i >> 8, k = i & 255;
        float v;
        if      (n < 32)  v = W_lc1[k * 32 + n];
        else if (n < 64)  v = W_lc2[k * 32 + (n - 32)];
        else if (n < 80)  v = W_mc [k * 16 + (n - 64)];
        else if (n < 144) v = W_hint[k * 64 + (n - 80)];
        else              v = 0.f;
        WlogT[i] = f2bf(v);
        return;
    }
    i -= 40960;
    if (i < 160) {
        float v;
        if      (i < 32)  v = b_lc1[i];
        else if (i < 64)  v = b_lc2[i - 32];
        else if (i < 80)  v = b_mc [i - 64];
        else if (i < 144) v = b_hint[i - 80];
        else              v = 0.f;
        blog[i] = v;
        return;
    }
    i -= 160;
    if (i == 0) *fixflag = 0;
}

// ---------------------------------------------------------------------------
// G1: emb = relu(obs @ W_emb + b_emb)  (unchanged)
// ---------------------------------------------------------------------------
__global__ __launch_bounds__(256, 3) void k_gemm_obs(
    const float* __restrict__ A, const unsigned short* __restrict__ Bt,
    const float* __restrict__ bias, unsigned short* __restrict__ out)
{
    __shared__ unsigned short As[128][72];
    __shared__ unsigned short Bs[128][72];
    const int tid = threadIdx.x, w = tid >> 6, L = tid & 63;
    const int mq = (w >> 1) * 64, nq = (w & 1) * 64;
    const int m0 = blockIdx.x * 128, n0 = blockIdx.y * 128;
    const int sr = tid >> 1, sh = (tid & 1) * 32;
    const int lc = L & 15, lq8 = (L >> 4) * 8, lr = (L >> 4) * 4;

    f32x4 acc[4][4];
#pragma unroll
    for (int i = 0; i < 4; i++)
#pragma unroll
        for (int j = 0; j < 4; j++) acc[i][j] = 0;

    const float* Ag = A + (size_t)(m0 + sr) * 512 + sh;
    const unsigned short* Bg = Bt + (size_t)(n0 + sr) * 512 + sh;

    for (int kt = 0; kt < 512; kt += 64) {
#pragma unroll
        for (int c = 0; c < 32; c += 8) {
            f32x4 v0 = *(const f32x4*)(Ag + kt + c);
            f32x4 v1 = *(const f32x4*)(Ag + kt + c + 4);
            short8 pk;
            pk[0] = (short)f2bf(v0[0]); pk[1] = (short)f2bf(v0[1]);
            pk[2] = (short)f2bf(v0[2]); pk[3] = (short)f2bf(v0[3]);
            pk[4] = (short)f2bf(v1[0]); pk[5] = (short)f2bf(v1[1]);
            pk[6] = (short)f2bf(v1[2]); pk[7] = (short)f2bf(v1[3]);
            *(short8*)&As[sr][sh + c] = pk;
            *(short8*)&Bs[sr][sh + c] = *(const short8*)(Bg + kt + c);
        }
        __syncthreads();
#pragma unroll
        for (int ks = 0; ks < 2; ks++) {
            short8 a[4], b[4];
#pragma unroll
            for (int i = 0; i < 4; i++)
                a[i] = *(const short8*)&As[mq + i * 16 + lc][ks * 32 + lq8];
#pragma unroll
            for (int j = 0; j < 4; j++)
                b[j] = *(const short8*)&Bs[nq + j * 16 + lc][ks * 32 + lq8];
#pragma unroll
            for (int i = 0; i < 4; i++)
#pragma unroll
                for (int j = 0; j < 4; j++)
                    acc[i][j] = __builtin_amdgcn_mfma_f32_16x16x32_bf16(a[i], b[j], acc[i][j], 0, 0, 0);
        }
        __syncthreads();
    }
#pragma unroll
    for (int i = 0; i < 4; i++)
#pragma unroll
        for (int j = 0; j < 4; j++) {
            int col = n0 + nq + j * 16 + lc;
            float bv = bias[col];
#pragma unroll
            for (int rg = 0; rg < 4; rg++) {
                int row = m0 + mq + i * 16 + lr + rg;
                float v = acc[i][j][rg] + bv;
                v = fmaxf(v, 0.f);
                out[(size_t)row * 256 + col] = f2bf(v);
            }
        }
}

// ---------------------------------------------------------------------------
// Generic bf16-A GEMM, K=256  (used for G3)
// ---------------------------------------------------------------------------
__global__ __launch_bounds__(256, 3) void k_gemm_bf(
    const unsigned short* __restrict__ A, const unsigned short* __restrict__ Bt,
    const float* __restrict__ biasA, const float* __restrict__ biasB,
    int nsplit, int relu, int N, unsigned short* __restrict__ out)
{
    __shared__ unsigned short As[128][72];
    __shared__ unsigned short Bs[128][72];
    const int tid = threadIdx.x, w = tid >> 6, L = tid & 63;
    const int mq = (w >> 1) * 64, nq = (w & 1) * 64;
    const int m0 = blockIdx.x * 128, n0 = blockIdx.y * 128;
    const int sr = tid >> 1, sh = (tid & 1) * 32;
    const int lc = L & 15, lq8 = (L >> 4) * 8, lr = (L >> 4) * 4;

    f32x4 acc[4][4];
#pragma unroll
    for (int i = 0; i < 4; i++)
#pragma unroll
        for (int j = 0; j < 4; j++) acc[i][j] = 0;

    const unsigned short* Ag = A + (size_t)(m0 + sr) * 256 + sh;
    const unsigned short* Bg = Bt + (size_t)(n0 + sr) * 256 + sh;

    for (int kt = 0; kt < 256; kt += 64) {
#pragma unroll
        for (int c = 0; c < 32; c += 8) {
            *(short8*)&As[sr][sh + c] = *(const short8*)(Ag + kt + c);
            *(short8*)&Bs[sr][sh + c] = *(const short8*)(Bg + kt + c);
        }
        __syncthreads();
#pragma unroll
        for (int ks = 0; ks < 2; ks++) {
            short8 a[4], b[4];
#pragma unroll
            for (int i = 0; i < 4; i++)
                a[i] = *(const short8*)&As[mq + i * 16 + lc][ks * 32 + lq8];
#pragma unroll
            for (int j = 0; j < 4; j++)
                b[j] = *(const short8*)&Bs[nq + j * 16 + lc][ks * 32 + lq8];
#pragma unroll
            for (int i = 0; i < 4; i++)
#pragma unroll
                for (int j = 0; j < 4; j++)
                    acc[i][j] = __builtin_amdgcn_mfma_f32_16x16x32_bf16(a[i], b[j], acc[i][j], 0, 0, 0);
        }
        __syncthreads();
    }
#pragma unroll
    for (int i = 0; i < 4; i++)
#pragma unroll
        for (int j = 0; j < 4; j++) {
            int col = n0 + nq + j * 16 + lc;
            float bv = (col < nsplit) ? biasA[col] : biasB[col - nsplit];
#pragma unroll
            for (int rg = 0; rg < 4; rg++) {
                int row = m0 + mq + i * 16 + lr + rg;
                float v = acc[i][j][rg] + bv;
                if (relu) v = fmaxf(v, 0.f);
                out[(size_t)row * N + col] = f2bf(v);
            }
        }
}

// ---------------------------------------------------------------------------
// G2: gi = emb @ Wi + bi, written directly in GRU-packed gate-plane layout:
//   out[gate*GIPL + ((t*16+g)*512 + tid)*8 + (r*2+s)]
// where tid/w/L/rowg/lc match the GRU thread that consumes the value.
// Each thread's acc already holds complete 8-element units -> dwordx4 stores,
// lane-consecutive (1KB bursts).
// ---------------------------------------------------------------------------
__global__ __launch_bounds__(256, 3) void k_gemm_gi(
    const unsigned short* __restrict__ A, const unsigned short* __restrict__ Bt,
    const float* __restrict__ bias, unsigned short* __restrict__ out)
{
    __shared__ unsigned short As[128][72];
    __shared__ unsigned short Bs[128][72];
    const int tid = threadIdx.x, w = tid >> 6, L = tid & 63;
    const int mq = (w >> 1) * 64, nq = (w & 1) * 64;
    const int m0 = blockIdx.x * 128, n0 = blockIdx.y * 128;
    const int sr = tid >> 1, sh = (tid & 1) * 32;
    const int lc = L & 15, lq8 = (L >> 4) * 8, lr = (L >> 4) * 4;

    f32x4 acc[4][4];
#pragma unroll
    for (int i = 0; i < 4; i++)
#pragma unroll
        for (int j = 0; j < 4; j++) acc[i][j] = 0;

    const unsigned short* Ag = A + (size_t)(m0 + sr) * 256 + sh;
    const unsigned short* Bg = Bt + (size_t)(n0 + sr) * 256 + sh;

    for (int kt = 0; kt < 256; kt += 64) {
#pragma unroll
        for (int c = 0; c < 32; c += 8) {
            *(short8*)&As[sr][sh + c] = *(const short8*)(Ag + kt + c);
            *(short8*)&Bs[sr][sh + c] = *(const short8*)(Bg + kt + c);
        }
        __syncthreads();
#pragma unroll
        for (int ks = 0; ks < 2; ks++) {
            short8 a[4], b[4];
#pragma unroll
            for (int i = 0; i < 4; i++)
                a[i] = *(const short8*)&As[mq + i * 16 + lc][ks * 32 + lq8];
#pragma unroll
            for (int j = 0; j < 4; j++)
                b[j] = *(const short8*)&Bs[nq + j * 16 + lc][ks * 32 + lq8];
#pragma unroll
            for (int i = 0; i < 4; i++)
#pragma unroll
                for (int j = 0; j < 4; j++)
                    acc[i][j] = __builtin_amdgcn_mfma_f32_16x16x32_bf16(a[i], b[j], acc[i][j], 0, 0, 0);
        }
        __syncthreads();
    }
    // packed epilogue: unit (i, jh) -> 8 bf16 = (rg,s) pairs
#pragma unroll
    for (int i = 0; i < 4; i++) {
        const int row0  = m0 + mq + i * 16 + lr;        // + rg (0..3)
        const int t     = row0 >> 8;
        const int g     = (row0 >> 4) & 15;
        const int rowg2 = (row0 >> 2) & 3;
#pragma unroll
        for (int jh = 0; jh < 2; jh++) {
            const int colb = n0 + nq + jh * 32;          // + s*16 + lc
            const int gate = colb >> 8;
            const int w2   = (colb & 255) >> 5;
            short8 pk;
#pragma unroll
            for (int rg = 0; rg < 4; rg++)
#pragma unroll
                for (int s = 0; s < 2; s++) {
                    int col = colb + s * 16 + lc;
                    float v = acc[i][jh * 2 + s][rg] + bias[col];
                    pk[rg * 2 + s] = (short)f2bf(v);
                }
            size_t dst = (size_t)gate * GIPL +
                         (((size_t)(t * 16 + g) * 512) + (size_t)w2 * 64 +
                          (size_t)rowg2 * 16 + lc) * 8;
            *(short8*)(out + dst) = pk;
        }
    }
}

// ---------------------------------------------------------------------------
// GRU main pass: 256 WGs = (batch-tile g = x&15) x (chunk c = x>>4).
// Speculates carry-in = 0 for c>0 (chunk 0 uses true h0). Stores h_end[c].
// gi: 3x short8 per thread per step, prefetched one step ahead.
// y:  staged in LDS, stored as one 16B full-line write per thread per step.
// ---------------------------------------------------------------------------
__global__ __launch_bounds__(512, 1) void k_gru_main(
    const unsigned short* __restrict__ gi, const unsigned short* __restrict__ WhF,
    const int* __restrict__ dones, const float* __restrict__ h0,
    const float* __restrict__ bhn, unsigned short* __restrict__ y,
    unsigned short* __restrict__ hend)
{
    __shared__ unsigned short hT[2][16][264];
    __shared__ unsigned short yS[2][16][256];
    __shared__ unsigned int rowbits[16];      // bit t' of dones for each row
    const int tid = threadIdx.x, w = tid >> 6, L = tid & 63;
    const int g = blockIdx.x & 15, c = blockIdx.x >> 4;
    const int b0 = g * 16, t0 = c * CHUNK;
    const int rowg = L >> 4, lc = L & 15;

    short8 Bf[6][8];
#pragma unroll
    for (int i6 = 0; i6 < 6; i6++)
#pragma unroll
        for (int ks = 0; ks < 8; ks++)
            Bf[i6][ks] = *(const short8*)(WhF + ((((size_t)w * 6 + i6) * 8 + ks) * 64 + L) * 8);

    const float bh0 = bhn[w * 32 + lc], bh1 = bhn[w * 32 + 16 + lc];

    // build dones bitmask for this chunk
    if (tid < 16) rowbits[tid] = 0;
    __syncthreads();
    {
        int tp = tid >> 4, r = tid & 15;
        if (dones[(t0 + tp) * 256 + b0 + r]) atomicOr(&rowbits[r], 1u << tp);
    }
    __syncthreads();

    unsigned rbr[4];
#pragma unroll
    for (int r = 0; r < 4; r++) rbr[r] = rowbits[rowg * 4 + r];

    // init h: c==0 -> h0 with done[0] reset; c>0 -> speculative 0
    {
        int hrow = tid >> 5, hcol = (tid & 31) * 8;
        bool rz = (rowbits[hrow] & 1u) != 0;
#pragma unroll
        for (int cc = 0; cc < 8; cc++) {
            unsigned short v = 0;
            if (c == 0 && !rz) v = f2bf(h0[(b0 + hrow) * 256 + hcol + cc]);
            hT[0][hrow][hcol + cc] = v;
        }
    }
    __syncthreads();

    // gi packed base for this thread: ((t*16+g)*512 + tid)*8, t = t0+tp
    const size_t gstep = (size_t)16 * 512 * 8;
    size_t gb = ((size_t)(t0 * 16 + g) * 512 + tid) * 8;
    short8 vir = *(const short8*)(gi + gb);
    short8 viz = *(const short8*)(gi + GIPL + gb);
    short8 vin = *(const short8*)(gi + 2 * GIPL + gb);

#pragma unroll 2
    for (int tp = 0; tp < CHUNK; tp++) {
        const int cur = tp & 1, nxt = cur ^ 1;
        const int t = t0 + tp;

        // prefetch next step's gi (independent of h)
        short8 nir, niz, nin;
        if (tp + 1 < CHUNK) {
            size_t gn = gb + (size_t)(tp + 1) * gstep;
            nir = *(const short8*)(gi + gn);
            niz = *(const short8*)(gi + GIPL + gn);
            nin = *(const short8*)(gi + 2 * GIPL + gn);
        }

        f32x4 acc0 = 0, acc1 = 0, acc2 = 0, acc3 = 0, acc4 = 0, acc5 = 0;
#pragma unroll
        for (int ks = 0; ks < 8; ks++) {
            short8 a = *(const short8*)&hT[cur][lc][ks * 32 + rowg * 8];
            acc0 = __builtin_amdgcn_mfma_f32_16x16x32_bf16(a, Bf[0][ks], acc0, 0, 0, 0);
            acc1 = __builtin_amdgcn_mfma_f32_16x16x32_bf16(a, Bf[1][ks], acc1, 0, 0, 0);
            acc2 = __builtin_amdgcn_mfma_f32_16x16x32_bf16(a, Bf[2][ks], acc2, 0, 0, 0);
            acc3 = __builtin_amdgcn_mfma_f32_16x16x32_bf16(a, Bf[3][ks], acc3, 0, 0, 0);
            acc4 = __builtin_amdgcn_mfma_f32_16x16x32_bf16(a, Bf[4][ks], acc4, 0, 0, 0);
            acc5 = __builtin_amdgcn_mfma_f32_16x16x32_bf16(a, Bf[5][ks], acc5, 0, 0, 0);
        }

#pragma unroll
        for (int s = 0; s < 2; s++) {
            const int j = w * 32 + s * 16 + lc;
            f32x4 hrv = s ? acc1 : acc0;
            f32x4 hzv = s ? acc3 : acc2;
            f32x4 hnv = s ? acc5 : acc4;
            float bh = s ? bh1 : bh0;
#pragma unroll
            for (int r = 0; r < 4; r++) {
                int row = rowg * 4 + r;
                float ir  = bf2f((unsigned short)vir[r * 2 + s]);
                float iz  = bf2f((unsigned short)viz[r * 2 + s]);
                float inn = bf2f((unsigned short)vin[r * 2 + s]);
                float ho  = bf2f(hT[cur][row][j]);
                unsigned short hb = gru_cell(ir, iz, inn, ho, hrv[r], hzv[r], hnv[r], bh);
                yS[cur][row][j] = hb;
                unsigned short hw = hb;
                if (tp + 1 < CHUNK && ((rbr[r] >> (tp + 1)) & 1u)) hw = 0;
                hT[nxt][row][j] = hw;
            }
        }
        __syncthreads();

        // coalesced y store (one 16B full-line write per thread)
        {
            int yrow = tid >> 5, ycol = (tid & 31) * 8;
            short8 yv = *(const short8*)&yS[cur][yrow][ycol];
            *(short8*)(y + ((size_t)t * 256 + b0 + yrow) * 256 + ycol) = yv;
            if (tp == CHUNK - 1)
                *(short8*)(hend + ((size_t)c * 256 + b0 + yrow) * 256 + ycol) = yv;
        }

        vir = nir; viz = niz; vin = nin;
    }
}

// ---------------------------------------------------------------------------
// PARALLEL GRU fixup: 240 WGs = (chunk c=1..15) x (16 batch-tiles).
// Carry-in = speculative hend[c-1], exact for rows with >=1 done in c-1.
// Violation (prob 2^-32/row/chunk) raises *flag -> sequential fallback.
// ---------------------------------------------------------------------------
__global__ __launch_bounds__(512, 1) void k_gru_fix_par(
    const unsigned short* __restrict__ gi, const unsigned short* __restrict__ WhF,
    const int* __restrict__ dones, const float* __restrict__ bhn,
    const unsigned short* __restrict__ hend, unsigned short* __restrict__ y,
    int* __restrict__ flag)
{
    __shared__ unsigned short hT[2][16][264];
    __shared__ unsigned int rowbits[16], prevbits[16];
    __shared__ int sh_fd[16];
    const int tid = threadIdx.x, w = tid >> 6, L = tid & 63;
    const int g = blockIdx.x & 15, c = (blockIdx.x >> 4) + 1;
    const int b0 = g * 16, t0 = c * CHUNK;
    const int rowg = L >> 4, lc = L & 15;
    const int hrow = tid >> 5, hcol = (tid & 31) * 8;

    short8 Bf[6][8];
#pragma unroll
    for (int i6 = 0; i6 < 6; i6++)
#pragma unroll
        for (int ks = 0; ks < 8; ks++)
            Bf[i6][ks] = *(const short8*)(WhF + ((((size_t)w * 6 + i6) * 8 + ks) * 64 + L) * 8);

    const float bh0 = bhn[w * 32 + lc], bh1 = bhn[w * 32 + 16 + lc];

    if (tid < 16) { rowbits[tid] = 0; prevbits[tid] = 0; }
    __syncthreads();
    {
        int tp = tid >> 4, r = tid & 15;
        if (dones[(t0 + tp) * 256 + b0 + r])         atomicOr(&rowbits[r],  1u << tp);
        if (dones[(t0 - CHUNK + tp) * 256 + b0 + r]) atomicOr(&prevbits[r], 1u << tp);
    }
    __syncthreads();
    if (tid < 16) {
        unsigned m = rowbits[tid];
        sh_fd[tid] = m ? __builtin_ctz(m) : CHUNK;
        if (prevbits[tid] == 0) atomicOr(flag, 1);   // carry-in untrusted
    }
    __syncthreads();

    int maxfix = 0;
    unsigned rbr[4]; int fdr[4];
#pragma unroll
    for (int r = 0; r < 16; r++) maxfix = max(maxfix, sh_fd[r]);
    if (maxfix == 0) return;                          // all rows reset at step 0
#pragma unroll
    for (int r = 0; r < 4; r++) {
        rbr[r] = rowbits[rowg * 4 + r];
        fdr[r] = sh_fd[rowg * 4 + r];
    }

    // carry-in: speculative end of chunk c-1, with chunk-c step-0 reset
    {
        short8 hv = *(const short8*)(hend + ((size_t)(c - 1) * 256 + b0 + hrow) * 256 + hcol);
        if (rowbits[hrow] & 1u) { short8 z = {0,0,0,0,0,0,0,0}; hv = z; }
        *(short8*)&hT[0][hrow][hcol] = hv;
    }
    __syncthreads();

    const size_t gstep = (size_t)16 * 512 * 8;
    const size_t gb0 = ((size_t)(t0 * 16 + g) * 512 + tid) * 8;

    int cur = 0;
    for (int tp = 0; tp < maxfix; tp++) {
        const int nxt = cur ^ 1;

        f32x4 acc0 = 0, acc1 = 0, acc2 = 0, acc3 = 0, acc4 = 0, acc5 = 0;
#pragma unroll
        for (int ks = 0; ks < 8; ks++) {
            short8 a = *(const short8*)&hT[cur][lc][ks * 32 + rowg * 8];
            acc0 = __builtin_amdgcn_mfma_f32_16x16x32_bf16(a, Bf[0][ks], acc0, 0, 0, 0);
            acc1 = __builtin_amdgcn_mfma_f32_16x16x32_bf16(a, Bf[1][ks], acc1, 0, 0, 0);
            acc2 = __builtin_amdgcn_mfma_f32_16x16x32_bf16(a, Bf[2][ks], acc2, 0, 0, 0);
            acc3 = __builtin_amdgcn_mfma_f32_16x16x32_bf16(a, Bf[3][ks], acc3, 0, 0, 0);
            acc4 = __builtin_amdgcn_mfma_f32_16x16x32_bf16(a, Bf[4][ks], acc4, 0, 0, 0);
            acc5 = __builtin_amdgcn_mfma_f32_16x16x32_bf16(a, Bf[5][ks], acc5, 0, 0, 0);
        }

        size_t gb = gb0 + (size_t)tp * gstep;
        short8 vir = *(const short8*)(gi + gb);
        short8 viz = *(const short8*)(gi + GIPL + gb);
        short8 vin = *(const short8*)(gi + 2 * GIPL + gb);

        unsigned short* yb = y + (size_t)((t0 + tp) * 256 + b0) * 256;
#pragma unroll
        for (int s = 0; s < 2; s++) {
            const int j = w * 32 + s * 16 + lc;
            f32x4 hrv = s ? acc1 : acc0;
            f32x4 hzv = s ? acc3 : acc2;
            f32x4 hnv = s ? acc5 : acc4;
            float bh = s ? bh1 : bh0;
#pragma unroll
            for (int r = 0; r < 4; r++) {
                int row = rowg * 4 + r;
                float ir  = bf2f((unsigned short)vir[r * 2 + s]);
                float iz  = bf2f((unsigned short)viz[r * 2 + s]);
                float inn = bf2f((unsigned short)vin[r * 2 + s]);
                float ho  = bf2f(hT[cur][row][j]);
                unsigned short hb = gru_cell(ir, iz, inn, ho, hrv[r], hzv[r], hnv[r], bh);
                if (tp < fdr[r]) yb[row * 256 + j] = hb;   // only fix wrong prefix
                unsigned short hw = hb;
                if (tp + 1 < CHUNK && ((rbr[r] >> (tp + 1)) & 1u)) hw = 0;
                hT[nxt][row][j] = hw;
            }
        }
        __syncthreads();
        cur = nxt;
    }
}

// ---------------------------------------------------------------------------
// GRU fixup FALLBACK (sequential over chunks): only runs if flag was set.
// ---------------------------------------------------------------------------
__global__ __launch_bounds__(512, 1) void k_gru_fix(
    const unsigned short* __restrict__ gi, const unsigned short* __restrict__ WhF,
    const int* __restrict__ dones, const float* __restrict__ bhn,
    const unsigned short* __restrict__ hend, unsigned short* __restrict__ y,
    const int* __restrict__ flag)
{
    if (*flag == 0) return;                   // uniform: common case, exit fast

    __shared__ unsigned short hT[2][16][264];
    __shared__ unsigned int rowbits[16];
    __shared__ int sh_fd[16];
    const int tid = threadIdx.x, w = tid >> 6, L = tid & 63;
    const int b0 = blockIdx.x * 16, g = blockIdx.x;
    const int rowg = L >> 4, lc = L & 15;
    const int hrow = tid >> 5, hcol = (tid & 31) * 8;

    short8 Bf[6][8];
#pragma unroll
    for (int i6 = 0; i6 < 6; i6++)
#pragma unroll
        for (int ks = 0; ks < 8; ks++)
            Bf[i6][ks] = *(const short8*)(WhF + ((((size_t)w * 6 + i6) * 8 + ks) * 64 + L) * 8);

    const float bh0 = bhn[w * 32 + lc], bh1 = bhn[w * 32 + 16 + lc];

    // carry = corrected end of chunk 0 (chunk 0 speculation used true h0)
    *(short8*)&hT[0][hrow][hcol] =
        *(const short8*)(hend + (size_t)(b0 + hrow) * 256 + hcol);
    int cur = 0;

    const size_t gstep = (size_t)16 * 512 * 8;

    for (int c = 1; c < NCH; c++) {
        const int t0 = c * CHUNK;
        if (tid < 16) rowbits[tid] = 0;
        __syncthreads();
        {
            int tp = tid >> 4, r = tid & 15;
            if (dones[(t0 + tp) * 256 + b0 + r]) atomicOr(&rowbits[r], 1u << tp);
        }
        __syncthreads();
        if (tid < 16) {
            unsigned m = rowbits[tid];
            sh_fd[tid] = m ? __builtin_ctz(m) : CHUNK;
        }
        __syncthreads();

        int maxfix = 0;
        unsigned rbr[4]; int fdr[4];
#pragma unroll
        for (int r = 0; r < 16; r++) maxfix = max(maxfix, sh_fd[r]);
#pragma unroll
        for (int r = 0; r < 4; r++) {
            rbr[r] = rowbits[rowg * 4 + r];
            fdr[r] = sh_fd[rowg * 4 + r];
        }
        // apply this chunk's step-0 reset to the carry
        if (rowbits[hrow] & 1u) {
#pragma unroll
            for (int cc = 0; cc < 8; cc++) hT[cur][hrow][hcol + cc] = 0;
        }
        __syncthreads();

        const size_t gb0 = ((size_t)(t0 * 16 + g) * 512 + tid) * 8;

        for (int tp = 0; tp < maxfix; tp++) {
            const int nxt = cur ^ 1;

            f32x4 acc0 = 0, acc1 = 0, acc2 = 0, acc3 = 0, acc4 = 0, acc5 = 0;
#pragma unroll
            for (int ks = 0; ks < 8; ks++) {
                short8 a = *(const short8*)&hT[cur][lc][ks * 32 + rowg * 8];
                acc0 = __builtin_amdgcn_mfma_f32_16x16x32_bf16(a, Bf[0][ks], acc0, 0, 0, 0);
                acc1 = __builtin_amdgcn_mfma_f32_16x16x32_bf16(a, Bf[1][ks], acc1, 0, 0, 0);
                acc2 = __builtin_amdgcn_mfma_f32_16x16x32_bf16(a, Bf[2][ks], acc2, 0, 0, 0);
                acc3 = __builtin_amdgcn_mfma_f32_16x16x32_bf16(a, Bf[3][ks], acc3, 0, 0, 0);
                acc4 = __builtin_amdgcn_mfma_f32_16x16x32_bf16(a, Bf[4][ks], acc4, 0, 0, 0);
                acc5 = __builtin_amdgcn_mfma_f32_16x16x32_bf16(a, Bf[5][ks], acc5, 0, 0, 0);
            }

            size_t gb = gb0 + (size_t)tp * gstep;
            short8 vir = *(const short8*)(gi + gb);
            short8 viz = *(const short8*)(gi + GIPL + gb);
            short8 vin = *(const short8*)(gi + 2 * GIPL + gb);

            unsigned short* yb = y + (size_t)((t0 + tp) * 256 + b0) * 256;
#pragma unroll
            for (int s = 0; s < 2; s++) {
                const int j = w * 32 + s * 16 + lc;
                f32x4 hrv = s ? acc1 : acc0;
                f32x4 hzv = s ? acc3 : acc2;
                f32x4 hnv = s ? acc5 : acc4;
                float bh = s ? bh1 : bh0;
#pragma unroll
                for (int r = 0; r < 4; r++) {
                    int row = rowg * 4 + r;
                    float ir  = bf2f((unsigned short)vir[r * 2 + s]);
                    float iz  = bf2f((unsigned short)viz[r * 2 + s]);
                    float inn = bf2f((unsigned short)vin[r * 2 + s]);
                    float ho  = bf2f(hT[cur][row][j]);
                    unsigned short hb = gru_cell(ir, iz, inn, ho, hrv[r], hzv[r], hnv[r], bh);
                    if (tp < fdr[r]) yb[row * 256 + j] = hb;   // only fix wrong prefix
                    unsigned short hw = hb;
                    if (tp + 1 < CHUNK && ((rbr[r] >> (tp + 1)) & 1u)) hw = 0;
                    hT[nxt][row][j] = hw;
                }
            }
            __syncthreads();
            cur = nxt;
        }

        // splice: rows that saw a done have correct speculative h_end
        if (sh_fd[hrow] < CHUNK) {
            *(short8*)&hT[cur][hrow][hcol] =
                *(const short8*)(hend + ((size_t)c * 256 + b0 + hrow) * 256 + hcol);
        }
        __syncthreads();
    }
}

// ---------------------------------------------------------------------------
// G4: logits (unchanged)
// ---------------------------------------------------------------------------
__global__ __launch_bounds__(256, 2) void k_logits(
    const unsigned short* __restrict__ ac, const unsigned short* __restrict__ Bt,
    const float* __restrict__ blog,
    const int* __restrict__ av1, const int* __restrict__ av2,
    const int* __restrict__ av3, const int* __restrict__ av4,
    float* __restrict__ outp)
{
    __shared__ unsigned short As[128][72];
    __shared__ unsigned short Bs[160][72];
    const int tid = threadIdx.x, w = tid >> 6, L = tid & 63;
    const int m0 = blockIdx.x * 128;
    const int sr = tid >> 1, sh = (tid & 1) * 32;
    const int lc = L & 15, lq8 = (L >> 4) * 8, lr = (L >> 4) * 4;

    f32x4 acc[2][10];
#pragma unroll
    for (int i = 0; i < 2; i++)
#pragma unroll
        for (int j = 0; j < 10; j++) acc[i][j] = 0;

    const unsigned short* Ag = ac + (size_t)(m0 + sr) * 512 + sh;

    for (int kt = 0; kt < 256; kt += 64) {
#pragma unroll
        for (int c = 0; c < 32; c += 8)
            *(short8*)&As[sr][sh + c] = *(const short8*)(Ag + kt + c);
        for (int u = tid; u < 320; u += 256) {
            int br = u >> 1, bh2 = (u & 1) * 32;
#pragma unroll
            for (int c = 0; c < 32; c += 8)
                *(short8*)&Bs[br][bh2 + c] = *(const short8*)(Bt + (size_t)br * 256 + kt + bh2 + c);
        }
        __syncthreads();
#pragma unroll
        for (int ks = 0; ks < 2; ks++) {
            short8 a[2], b[10];
#pragma unroll
            for (int i = 0; i < 2; i++)
                a[i] = *(const short8*)&As[w * 32 + i * 16 + lc][ks * 32 + lq8];
#pragma unroll
            for (int j = 0; j < 10; j++)
                b[j] = *(const short8*)&Bs[j * 16 + lc][ks * 32 + lq8];
#pragma unroll
            for (int i = 0; i < 2; i++)
#pragma unroll
                for (int j = 0; j < 10; j++)
                    acc[i][j] = __builtin_amdgcn_mfma_f32_16x16x32_bf16(a[i], b[j], acc[i][j], 0, 0, 0);
        }
        __syncthreads();
    }
#pragma unroll
    for (int j = 0; j < 10; j++) {
        int col = j * 16 + lc;
        if (col >= 144) continue;
        int gbase, adim; const int* av; size_t obase;
        if      (col < 32) { gbase = 0;  adim = 32; av = av1; obase = OUT_LC1; }
        else if (col < 64) { gbase = 32; adim = 32; av = av2; obase = OUT_LC2; }
        else if (col < 80) { gbase = 64; adim = 16; av = av3; obase = OUT_MC;  }
        else               { gbase = 80; adim = 64; av = av4; obase = OUT_HINT;}
        int cof = col - gbase;
        float bv = blog[col];
#pragma unroll
        for (int i = 0; i < 2; i++)
#pragma unroll
            for (int rg = 0; rg < 4; rg++) {
                int R = m0 + w * 32 + i * 16 + lr + rg;
                float v = acc[i][j][rg] + bv;
                int a_ = av[(size_t)R * adim + cof];
                v -= (1.f - (float)a_) * 1e10f;
                outp[obase + (size_t)R * adim + cof] = v;
            }
    }
}

// ---------------------------------------------------------------------------
// G5: critic (unchanged)
// ---------------------------------------------------------------------------
__global__ __launch_bounds__(256, 4) void k_critic(
    const unsigned short* __restrict__ ac, const float* __restrict__ W_c2,
    const float* __restrict__ b_c2, float* __restrict__ outp)
{
    const int tid = threadIdx.x, w = tid >> 6, L = tid & 63;
    f32x4 wv = *(const f32x4*)(W_c2 + L * 4);
    float bb = b_c2[0];
    int base = blockIdx.x * 64 + w * 16;
    for (int rr = 0; rr < 16; rr++) {
        int R = base + rr;
        const unsigned short* p = ac + (size_t)R * 512 + 256 + L * 4;
        float s = bf2f(p[0]) * wv[0] + bf2f(p[1]) * wv[1] +
                  bf2f(p[2]) * wv[2] + bf2f(p[3]) * wv[3];
#pragma unroll
        for (int o = 32; o > 0; o >>= 1) s += __shfl_down(s, o);
        if (L == 0) outp[OUT_CRIT + R] = s + bb;
    }
}

__global__ __launch_bounds__(256, 4) void k_hidden(
    const unsigned short* __restrict__ y, float* __restrict__ outp)
{
    int i = blockIdx.x * 256 + threadIdx.x;
    outp[OUT_HID + i] = bf2f(y[(size_t)511 * 65536 + i]);
}

// ---------------------------------------------------------------------------
extern "C" void kernel_launch(void* const* d_in, const int* in_sizes, int n_in,
                              void* d_out, int out_size, void* d_ws, size_t ws_size,
                              hipStream_t stream)
{
    const float* hidden = (const float*)d_in[0];
    const float* obs    = (const float*)d_in[1];
    const int*   dones  = (const int*)d_in[2];
    const int*   av1    = (const int*)d_in[3];
    const int*   av2    = (const int*)d_in[4];
    const int*   av3    = (const int*)d_in[5];
    const int*   av4    = (const int*)d_in[6];
    const float* W_emb  = (const float*)d_in[7];
    const float* b_emb  = (const float*)d_in[8];
    const float* Wi     = (const float*)d_in[9];
    const float* bi     = (const float*)d_in[10];
    const float* Wh     = (const float*)d_in[11];
    const float* bhn    = (const float*)d_in[12];
    const float* W_a    = (const float*)d_in[13];
    const float* b_a    = (const float*)d_in[14];
    const float* W_lc1  = (const float*)d_in[15];
    const float* b_lc1  = (const float*)d_in[16];
    const float* W_lc2  = (const float*)d_in[17];
    const float* b_lc2  = (const float*)d_in[18];
    const float* W_mc   = (const float*)d_in[19];
    const float* b_mc   = (const float*)d_in[20];
    const float* W_hint = (const float*)d_in[21];
    const float* b_hint = (const float*)d_in[22];
    const float* W_c1   = (const float*)d_in[23];
    const float* b_c1   = (const float*)d_in[24];
    const float* W_c2   = (const float*)d_in[25];
    const float* b_c2   = (const float*)d_in[26];

    char* ws = (char*)d_ws;
    unsigned short* WembT = (unsigned short*)(ws + 0);
    unsigned short* WiT   = (unsigned short*)(ws + 262144);
    unsigned short* WhF   = (unsigned short*)(ws + 655360);
    unsigned short* WacT  = (unsigned short*)(ws + 1048576);
    unsigned short* WlogT = (unsigned short*)(ws + 1310720);
    float*          blog  = (float*)(ws + 1392640);
    int*            fflag = (int*)(ws + 1393280);
    // emb (TB x 256 bf16, 67 MB) / hend (2 MB) / ac (TB x 512 bf16, 134 MB)
    // share a region: emb dies after G2; hend lives only gru_main->gru_fix;
    // ac written by G3 after fixup.
    unsigned short* emb   = (unsigned short*)(ws + 1393664);
    unsigned short* hend  = emb;
    unsigned short* ac    = emb;
    unsigned short* gibuf = (unsigned short*)(ws + 135611392);
    unsigned short* ybuf  = (unsigned short*)(ws + 336937984);
    float* outp = (float*)d_out;

    k_prep<<<2721, 256, 0, stream>>>(W_emb, Wi, Wh, W_a, W_c1, W_lc1, W_lc2,
                                     W_mc, W_hint, b_lc1, b_lc2, b_mc, b_hint,
                                     WembT, WiT, WhF, WacT, WlogT, blog, fflag);
    k_gemm_obs<<<dim3(1024, 2), 256, 0, stream>>>(obs, WembT, b_emb, emb);
    k_gemm_gi<<<dim3(1024, 6), 256, 0, stream>>>(emb, WiT, bi, gibuf);
    k_gru_main<<<256, 512, 0, stream>>>(gibuf, WhF, dones, hidden, bhn, ybuf, hend);
    k_gru_fix_par<<<240, 512, 0, stream>>>(gibuf, WhF, dones, bhn, hend, ybuf, fflag);
    k_gru_fix<<<16, 512, 0, stream>>>(gibuf, WhF, dones, bhn, hend, ybuf, fflag);
    k_gemm_bf<<<dim3(1024, 4), 256, 0, stream>>>(ybuf, WacT, b_a, b_c1, 256, 1, 512, ac);
    k_logits<<<1024, 256, 0, stream>>>(ac, WlogT, blog, av1, av2, av3, av4, outp);
    k_critic<<<2048, 256, 0, stream>>>(ac, W_c2, b_c2, outp);
    k_hidden<<<2048 / 8, 256, 0, stream>>>(ybuf, outp);
}

// Round 3
// 922.366 us; speedup vs baseline: 1.6266x; 1.1091x over previous
//
#include <hip/hip_runtime.h>
#include <stdint.h>

// ---------------------------------------------------------------------------
// ActorCriticRNN on MI355X.
//   prep:  weights -> bf16 (B^T layout), Wh -> MFMA-fragment-linear.
//   G12:   FUSED: emb = relu(obs @ W_emb + b) computed per 64-row tile,
//          kept in LDS (never hits HBM), then gi = emb @ Wi + bi written
//          in GRU-packed gate-plane layout. obs read EXACTLY once.
//   GRU:   chunk-parallel speculation (dones p=0.5 reset h). Main: 256 WGs.
//          gi prefetched one step ahead; y staged in LDS, 16B/lane stores.
//          Fixup parallel over 240 (chunk,tile) WGs + sequential fallback
//          guarded by a flag (prob ~2^-32 per row-chunk).
//   G3:    k_gemm_ac: y tile staged to LDS once, [a|c] = relu(y@[W_a|W_c1]+b),
//          y read EXACTLY once (was 4x).
//   G4:    logits masked by avail; G5: critic dot; out0: hidden = y[T-1].
// ---------------------------------------------------------------------------

typedef short short8 __attribute__((ext_vector_type(8)));
typedef float f32x4  __attribute__((ext_vector_type(4)));

#define T_DIM 512
#define CHUNK 32
#define NCH   16
#define GIPL  ((size_t)33554432)   // gi gate-plane size in shorts (8192*512*8)

// output offsets (fp32 elements)
#define OUT_HID  ((size_t)0)
#define OUT_LC1  ((size_t)65536)
#define OUT_LC2  ((size_t)4259840)
#define OUT_MC   ((size_t)8454144)
#define OUT_HINT ((size_t)10551296)
#define OUT_CRIT ((size_t)18939904)

__device__ __forceinline__ unsigned short f2bf(float f) {
    unsigned u = __float_as_uint(f);
    u += 0x7fffu + ((u >> 16) & 1u);          // round-to-nearest-even
    return (unsigned short)(u >> 16);
}
__device__ __forceinline__ float bf2f(unsigned short h) {
    return __uint_as_float(((unsigned)h) << 16);
}

__device__ __forceinline__ unsigned short gru_cell(
    float ir, float iz, float inn, float ho,
    float hrv, float hzv, float hnv, float bh)
{
    float rg = 1.f / (1.f + __expf(-(ir + hrv)));
    float z  = 1.f / (1.f + __expf(-(iz + hzv)));
    float ex = __expf(2.f * (inn + rg * (hnv + bh)));
    float n  = 1.f - 2.f / (ex + 1.f);        // tanh, inf-safe
    return f2bf((1.f - z) * n + z * ho);
}

// ---------------------------------------------------------------------------
// prep (verified; + zero the fixup-fallback flag)
// ---------------------------------------------------------------------------
__global__ __launch_bounds__(256, 4) void k_prep(
    const float* __restrict__ W_emb, const float* __restrict__ Wi,
    const float* __restrict__ Wh,    const float* __restrict__ W_a,
    const float* __restrict__ W_c1,  const float* __restrict__ W_lc1,
    const float* __restrict__ W_lc2, const float* __restrict__ W_mc,
    const float* __restrict__ W_hint,
    const float* __restrict__ b_lc1, const float* __restrict__ b_lc2,
    const float* __restrict__ b_mc,  const float* __restrict__ b_hint,
    unsigned short* __restrict__ WembT, unsigned short* __restrict__ WiT,
    unsigned short* __restrict__ WhF,   unsigned short* __restrict__ WacT,
    unsigned short* __restrict__ WlogT, float* __restrict__ blog,
    int* __restrict__ fixflag)
{
    int i = blockIdx.x * 256 + threadIdx.x;
    if (i < 131072) {                         // WembT[n][k] = W_emb[k][n]
        int n = i >> 9, k = i & 511;
        WembT[i] = f2bf(W_emb[k * 256 + n]);
        return;
    }
    i -= 131072;
    if (i < 196608) {                         // WiT[n][k] = Wi[k][n]
        int n = i >> 8, k = i & 255;
        WiT[i] = f2bf(Wi[k * 768 + n]);
        return;
    }
    i -= 196608;
    if (i < 196608) {                         // Wh fragment-linear
        int jj = i & 7, L = (i >> 3) & 63, ks = (i >> 9) & 7, rest = i >> 12;
        int w = rest / 6, i6 = rest % 6, rho = i6 >> 1, s = i6 & 1;
        int k   = ks * 32 + ((L >> 4) << 3) + jj;
        int col = rho * 256 + w * 32 + s * 16 + (L & 15);
        WhF[i] = f2bf(Wh[k * 768 + col]);
        return;
    }
    i -= 196608;
    if (i < 131072) {                         // WacT
        int n = i >> 8, k = i & 255;
        WacT[i] = f2bf(n < 256 ? W_a[k * 256 + n] : W_c1[k * 256 + (n - 256)]);
        return;
    }
    i -= 131072;
    if (i < 40960) {                          // WlogT (N padded to 160)
        int n = i >> 8, k = i & 255;
        float v;
        if      (n < 32)  v = W_lc1[k * 32 + n];
        else if (n < 64)  v = W_lc2[k * 32 + (n - 32)];
        else if (n < 80)  v = W_mc [k * 16 + (n - 64)];
        else if (n < 144) v = W_hint[k * 64 + (n - 80)];
        else              v = 0.f;
        WlogT[i] = f2bf(v);
        return;
    }
    i -= 40960;
    if (i < 160) {
        float v;
        if      (i < 32)  v = b_lc1[i];
        else if (i < 64)  v = b_lc2[i - 32];
        else if (i < 80)  v = b_mc [i - 64];
        else if (i < 144) v = b_hint[i - 80];
        else              v = 0.f;
        blog[i] = v;
        return;
    }
    i -= 160;
    if (i == 0) *fixflag = 0;
}

// ---------------------------------------------------------------------------
// FUSED G1+G2: per 64-row tile (2048 blocks, 512 threads = 8 waves 2x4):
//   phase 1: emb = relu(obs @ WembT + b_emb), K=512, full N=256 -> LDS eS.
//   phase 2: for 3 gate-chunks: gi_chunk = eS @ WiT_chunk + bi, K=256,
//            written in GRU-packed layout (verified formulas from k_gemm_gi).
// obs read exactly once; emb never touches HBM.
// ---------------------------------------------------------------------------
__global__ __launch_bounds__(512, 4) void k_fused_g12(
    const float* __restrict__ obs, const unsigned short* __restrict__ WembT,
    const float* __restrict__ b_emb, const unsigned short* __restrict__ WiT,
    const float* __restrict__ bi, unsigned short* __restrict__ out)
{
    __shared__ unsigned short As[64][72];
    __shared__ unsigned short Bs[256][72];
    __shared__ unsigned short eS[64][264];
    const int tid = threadIdx.x, w = tid >> 6, L = tid & 63;
    const int mq = (w >> 2) * 32, nq = (w & 3) * 64;
    const int m0 = blockIdx.x * 64;
    const int lc = L & 15, lq8 = (L >> 4) * 8, lr = (L >> 4) * 4;
    const int sra = tid >> 3, sha = (tid & 7) * 8;   // As staging: 8 thr/row
    const int srb = tid >> 1, shb = (tid & 1) * 32;  // Bs staging: 2 thr/row

    f32x4 acc[2][4];
#pragma unroll
    for (int i = 0; i < 2; i++)
#pragma unroll
        for (int j = 0; j < 4; j++) acc[i][j] = 0;

    // ---- phase 1: emb tile ----
    const float* Ag = obs + (size_t)(m0 + sra) * 512 + sha;
    const unsigned short* Bg1 = WembT + (size_t)srb * 512 + shb;

    for (int kt = 0; kt < 512; kt += 64) {
        {
            f32x4 v0 = *(const f32x4*)(Ag + kt);
            f32x4 v1 = *(const f32x4*)(Ag + kt + 4);
            short8 pk;
            pk[0] = (short)f2bf(v0[0]); pk[1] = (short)f2bf(v0[1]);
            pk[2] = (short)f2bf(v0[2]); pk[3] = (short)f2bf(v0[3]);
            pk[4] = (short)f2bf(v1[0]); pk[5] = (short)f2bf(v1[1]);
            pk[6] = (short)f2bf(v1[2]); pk[7] = (short)f2bf(v1[3]);
            *(short8*)&As[sra][sha] = pk;
        }
#pragma unroll
        for (int c = 0; c < 32; c += 8)
            *(short8*)&Bs[srb][shb + c] = *(const short8*)(Bg1 + kt + c);
        __syncthreads();
#pragma unroll
        for (int ks = 0; ks < 2; ks++) {
            short8 a[2], b[4];
#pragma unroll
            for (int i = 0; i < 2; i++)
                a[i] = *(const short8*)&As[mq + i * 16 + lc][ks * 32 + lq8];
#pragma unroll
            for (int j = 0; j < 4; j++)
                b[j] = *(const short8*)&Bs[nq + j * 16 + lc][ks * 32 + lq8];
#pragma unroll
            for (int i = 0; i < 2; i++)
#pragma unroll
                for (int j = 0; j < 4; j++)
                    acc[i][j] = __builtin_amdgcn_mfma_f32_16x16x32_bf16(a[i], b[j], acc[i][j], 0, 0, 0);
        }
        __syncthreads();
    }
    // epilogue phase 1: relu -> bf16 -> eS
#pragma unroll
    for (int i = 0; i < 2; i++)
#pragma unroll
        for (int j = 0; j < 4; j++) {
            int col = nq + j * 16 + lc;
            float bv = b_emb[col];
#pragma unroll
            for (int rg = 0; rg < 4; rg++) {
                int row = mq + i * 16 + lr + rg;
                eS[row][col] = f2bf(fmaxf(acc[i][j][rg] + bv, 0.f));
            }
        }
    __syncthreads();

    // ---- phase 2: gi = eS @ WiT + bi, 3 gate chunks ----
    for (int nc = 0; nc < 3; nc++) {
#pragma unroll
        for (int i = 0; i < 2; i++)
#pragma unroll
            for (int j = 0; j < 4; j++) acc[i][j] = 0;

        const unsigned short* Bg2 = WiT + (size_t)(nc * 256 + srb) * 256 + shb;
        for (int kt = 0; kt < 256; kt += 64) {
#pragma unroll
            for (int c = 0; c < 32; c += 8)
                *(short8*)&Bs[srb][shb + c] = *(const short8*)(Bg2 + kt + c);
            __syncthreads();
#pragma unroll
            for (int ks = 0; ks < 2; ks++) {
                short8 a[2], b[4];
#pragma unroll
                for (int i = 0; i < 2; i++)
                    a[i] = *(const short8*)&eS[mq + i * 16 + lc][kt + ks * 32 + lq8];
#pragma unroll
                for (int j = 0; j < 4; j++)
                    b[j] = *(const short8*)&Bs[nq + j * 16 + lc][ks * 32 + lq8];
#pragma unroll
                for (int i = 0; i < 2; i++)
#pragma unroll
                    for (int j = 0; j < 4; j++)
                        acc[i][j] = __builtin_amdgcn_mfma_f32_16x16x32_bf16(a[i], b[j], acc[i][j], 0, 0, 0);
            }
            __syncthreads();
        }
        // packed epilogue (same verified formulas as k_gemm_gi)
#pragma unroll
        for (int i = 0; i < 2; i++) {
            const int row0  = m0 + mq + i * 16 + lr;
            const int t     = row0 >> 8;
            const int g     = (row0 >> 4) & 15;
            const int rowg2 = (row0 >> 2) & 3;
#pragma unroll
            for (int jh = 0; jh < 2; jh++) {
                const int colb = nc * 256 + nq + jh * 32;
                const int gate = colb >> 8;
                const int w2   = (colb & 255) >> 5;
                short8 pk;
#pragma unroll
                for (int rg = 0; rg < 4; rg++)
#pragma unroll
                    for (int s = 0; s < 2; s++) {
                        int col = colb + s * 16 + lc;
                        float v = acc[i][jh * 2 + s][rg] + bi[col];
                        pk[rg * 2 + s] = (short)f2bf(v);
                    }
                size_t dst = (size_t)gate * GIPL +
                             (((size_t)(t * 16 + g) * 512) + (size_t)w2 * 64 +
                              (size_t)rowg2 * 16 + lc) * 8;
                *(short8*)(out + dst) = pk;
            }
        }
        // no extra sync needed: epilogue touches no LDS; next staging waits
        // behind the kt-loop's trailing barrier semantics via per-kt syncs
        __syncthreads();
    }
}

// ---------------------------------------------------------------------------
// G3: [a|c] = relu(y @ [W_a|W_c1] + b). 2048 blocks x 64 rows, 512 threads.
// y tile staged to LDS ONCE (read exactly once from HBM), 2 N-chunks of 256.
// ---------------------------------------------------------------------------
__global__ __launch_bounds__(512, 4) void k_gemm_ac(
    const unsigned short* __restrict__ y, const unsigned short* __restrict__ WacT,
    const float* __restrict__ b_a, const float* __restrict__ b_c1,
    unsigned short* __restrict__ out)
{
    __shared__ unsigned short yS[64][264];
    __shared__ unsigned short Bs[256][72];
    const int tid = threadIdx.x, w = tid >> 6, L = tid & 63;
    const int mq = (w >> 2) * 32, nq = (w & 3) * 64;
    const int m0 = blockIdx.x * 64;
    const int lc = L & 15, lq8 = (L >> 4) * 8, lr = (L >> 4) * 4;
    const int srb = tid >> 1, shb = (tid & 1) * 32;

    // stage y tile once: 32 shorts/thread
    {
        int r = tid >> 3, cb = (tid & 7) * 32;
        const unsigned short* yg = y + (size_t)(m0 + r) * 256 + cb;
#pragma unroll
        for (int c = 0; c < 32; c += 8)
            *(short8*)&yS[r][cb + c] = *(const short8*)(yg + c);
    }

    f32x4 acc[2][4];
    for (int nc = 0; nc < 2; nc++) {
#pragma unroll
        for (int i = 0; i < 2; i++)
#pragma unroll
            for (int j = 0; j < 4; j++) acc[i][j] = 0;

        const unsigned short* Bg = WacT + (size_t)(nc * 256 + srb) * 256 + shb;
        for (int kt = 0; kt < 256; kt += 64) {
#pragma unroll
            for (int c = 0; c < 32; c += 8)
                *(short8*)&Bs[srb][shb + c] = *(const short8*)(Bg + kt + c);
            __syncthreads();   // also guards initial yS staging on first pass
#pragma unroll
            for (int ks = 0; ks < 2; ks++) {
                short8 a[2], b[4];
#pragma unroll
                for (int i = 0; i < 2; i++)
                    a[i] = *(const short8*)&yS[mq + i * 16 + lc][kt + ks * 32 + lq8];
#pragma unroll
                for (int j = 0; j < 4; j++)
                    b[j] = *(const short8*)&Bs[nq + j * 16 + lc][ks * 32 + lq8];
#pragma unroll
                for (int i = 0; i < 2; i++)
#pragma unroll
                    for (int j = 0; j < 4; j++)
                        acc[i][j] = __builtin_amdgcn_mfma_f32_16x16x32_bf16(a[i], b[j], acc[i][j], 0, 0, 0);
            }
            __syncthreads();
        }
#pragma unroll
        for (int i = 0; i < 2; i++)
#pragma unroll
            for (int j = 0; j < 4; j++) {
                int col = nc * 256 + nq + j * 16 + lc;
                float bv = (col < 256) ? b_a[col] : b_c1[col - 256];
#pragma unroll
                for (int rg = 0; rg < 4; rg++) {
                    int row = m0 + mq + i * 16 + lr + rg;
                    out[(size_t)row * 512 + col] = f2bf(fmaxf(acc[i][j][rg] + bv, 0.f));
                }
            }
        __syncthreads();
    }
}

// ---------------------------------------------------------------------------
// GRU main pass: 256 WGs = (batch-tile g = x&15) x (chunk c = x>>4).
// Speculates carry-in = 0 for c>0 (chunk 0 uses true h0). Stores h_end[c].
// gi: 3x short8 per thread per step, prefetched one step ahead.
// y:  staged in LDS, stored as one 16B full-line write per thread per step.
// ---------------------------------------------------------------------------
__global__ __launch_bounds__(512, 1) void k_gru_main(
    const unsigned short* __restrict__ gi, const unsigned short* __restrict__ WhF,
    const int* __restrict__ dones, const float* __restrict__ h0,
    const float* __restrict__ bhn, unsigned short* __restrict__ y,
    unsigned short* __restrict__ hend)
{
    __shared__ unsigned short hT[2][16][264];
    __shared__ unsigned short yS[2][16][256];
    __shared__ unsigned int rowbits[16];      // bit t' of dones for each row
    const int tid = threadIdx.x, w = tid >> 6, L = tid & 63;
    const int g = blockIdx.x & 15, c = blockIdx.x >> 4;
    const int b0 = g * 16, t0 = c * CHUNK;
    const int rowg = L >> 4, lc = L & 15;

    short8 Bf[6][8];
#pragma unroll
    for (int i6 = 0; i6 < 6; i6++)
#pragma unroll
        for (int ks = 0; ks < 8; ks++)
            Bf[i6][ks] = *(const short8*)(WhF + ((((size_t)w * 6 + i6) * 8 + ks) * 64 + L) * 8);

    const float bh0 = bhn[w * 32 + lc], bh1 = bhn[w * 32 + 16 + lc];

    // build dones bitmask for this chunk
    if (tid < 16) rowbits[tid] = 0;
    __syncthreads();
    {
        int tp = tid >> 4, r = tid & 15;
        if (dones[(t0 + tp) * 256 + b0 + r]) atomicOr(&rowbits[r], 1u << tp);
    }
    __syncthreads();

    unsigned rbr[4];
#pragma unroll
    for (int r = 0; r < 4; r++) rbr[r] = rowbits[rowg * 4 + r];

    // init h: c==0 -> h0 with done[0] reset; c>0 -> speculative 0
    {
        int hrow = tid >> 5, hcol = (tid & 31) * 8;
        bool rz = (rowbits[hrow] & 1u) != 0;
#pragma unroll
        for (int cc = 0; cc < 8; cc++) {
            unsigned short v = 0;
            if (c == 0 && !rz) v = f2bf(h0[(b0 + hrow) * 256 + hcol + cc]);
            hT[0][hrow][hcol + cc] = v;
        }
    }
    __syncthreads();

    // gi packed base for this thread: ((t*16+g)*512 + tid)*8, t = t0+tp
    const size_t gstep = (size_t)16 * 512 * 8;
    size_t gb = ((size_t)(t0 * 16 + g) * 512 + tid) * 8;
    short8 vir = *(const short8*)(gi + gb);
    short8 viz = *(const short8*)(gi + GIPL + gb);
    short8 vin = *(const short8*)(gi + 2 * GIPL + gb);

#pragma unroll 2
    for (int tp = 0; tp < CHUNK; tp++) {
        const int cur = tp & 1, nxt = cur ^ 1;
        const int t = t0 + tp;

        // prefetch next step's gi (independent of h)
        short8 nir, niz, nin;
        if (tp + 1 < CHUNK) {
            size_t gn = gb + (size_t)(tp + 1) * gstep;
            nir = *(const short8*)(gi + gn);
            niz = *(const short8*)(gi + GIPL + gn);
            nin = *(const short8*)(gi + 2 * GIPL + gn);
        }

        f32x4 acc0 = 0, acc1 = 0, acc2 = 0, acc3 = 0, acc4 = 0, acc5 = 0;
#pragma unroll
        for (int ks = 0; ks < 8; ks++) {
            short8 a = *(const short8*)&hT[cur][lc][ks * 32 + rowg * 8];
            acc0 = __builtin_amdgcn_mfma_f32_16x16x32_bf16(a, Bf[0][ks], acc0, 0, 0, 0);
            acc1 = __builtin_amdgcn_mfma_f32_16x16x32_bf16(a, Bf[1][ks], acc1, 0, 0, 0);
            acc2 = __builtin_amdgcn_mfma_f32_16x16x32_bf16(a, Bf[2][ks], acc2, 0, 0, 0);
            acc3 = __builtin_amdgcn_mfma_f32_16x16x32_bf16(a, Bf[3][ks], acc3, 0, 0, 0);
            acc4 = __builtin_amdgcn_mfma_f32_16x16x32_bf16(a, Bf[4][ks], acc4, 0, 0, 0);
            acc5 = __builtin_amdgcn_mfma_f32_16x16x32_bf16(a, Bf[5][ks], acc5, 0, 0, 0);
        }

#pragma unroll
        for (int s = 0; s < 2; s++) {
            const int j = w * 32 + s * 16 + lc;
            f32x4 hrv = s ? acc1 : acc0;
            f32x4 hzv = s ? acc3 : acc2;
            f32x4 hnv = s ? acc5 : acc4;
            float bh = s ? bh1 : bh0;
#pragma unroll
            for (int r = 0; r < 4; r++) {
                int row = rowg * 4 + r;
                float ir  = bf2f((unsigned short)vir[r * 2 + s]);
                float iz  = bf2f((unsigned short)viz[r * 2 + s]);
                float inn = bf2f((unsigned short)vin[r * 2 + s]);
                float ho  = bf2f(hT[cur][row][j]);
                unsigned short hb = gru_cell(ir, iz, inn, ho, hrv[r], hzv[r], hnv[r], bh);
                yS[cur][row][j] = hb;
                unsigned short hw = hb;
                if (tp + 1 < CHUNK && ((rbr[r] >> (tp + 1)) & 1u)) hw = 0;
                hT[nxt][row][j] = hw;
            }
        }
        __syncthreads();

        // coalesced y store (one 16B full-line write per thread)
        {
            int yrow = tid >> 5, ycol = (tid & 31) * 8;
            short8 yv = *(const short8*)&yS[cur][yrow][ycol];
            *(short8*)(y + ((size_t)t * 256 + b0 + yrow) * 256 + ycol) = yv;
            if (tp == CHUNK - 1)
                *(short8*)(hend + ((size_t)c * 256 + b0 + yrow) * 256 + ycol) = yv;
        }

        vir = nir; viz = niz; vin = nin;
    }
}

// ---------------------------------------------------------------------------
// PARALLEL GRU fixup: 240 WGs = (chunk c=1..15) x (16 batch-tiles).
// Carry-in = speculative hend[c-1], exact for rows with >=1 done in c-1.
// Violation (prob 2^-32/row/chunk) raises *flag -> sequential fallback.
// ---------------------------------------------------------------------------
__global__ __launch_bounds__(512, 1) void k_gru_fix_par(
    const unsigned short* __restrict__ gi, const unsigned short* __restrict__ WhF,
    const int* __restrict__ dones, const float* __restrict__ bhn,
    const unsigned short* __restrict__ hend, unsigned short* __restrict__ y,
    int* __restrict__ flag)
{
    __shared__ unsigned short hT[2][16][264];
    __shared__ unsigned int rowbits[16], prevbits[16];
    __shared__ int sh_fd[16];
    const int tid = threadIdx.x, w = tid >> 6, L = tid & 63;
    const int g = blockIdx.x & 15, c = (blockIdx.x >> 4) + 1;
    const int b0 = g * 16, t0 = c * CHUNK;
    const int rowg = L >> 4, lc = L & 15;
    const int hrow = tid >> 5, hcol = (tid & 31) * 8;

    short8 Bf[6][8];
#pragma unroll
    for (int i6 = 0; i6 < 6; i6++)
#pragma unroll
        for (int ks = 0; ks < 8; ks++)
            Bf[i6][ks] = *(const short8*)(WhF + ((((size_t)w * 6 + i6) * 8 + ks) * 64 + L) * 8);

    const float bh0 = bhn[w * 32 + lc], bh1 = bhn[w * 32 + 16 + lc];

    if (tid < 16) { rowbits[tid] = 0; prevbits[tid] = 0; }
    __syncthreads();
    {
        int tp = tid >> 4, r = tid & 15;
        if (dones[(t0 + tp) * 256 + b0 + r])         atomicOr(&rowbits[r],  1u << tp);
        if (dones[(t0 - CHUNK + tp) * 256 + b0 + r]) atomicOr(&prevbits[r], 1u << tp);
    }
    __syncthreads();
    if (tid < 16) {
        unsigned m = rowbits[tid];
        sh_fd[tid] = m ? __builtin_ctz(m) : CHUNK;
        if (prevbits[tid] == 0) atomicOr(flag, 1);   // carry-in untrusted
    }
    __syncthreads();

    int maxfix = 0;
    unsigned rbr[4]; int fdr[4];
#pragma unroll
    for (int r = 0; r < 16; r++) maxfix = max(maxfix, sh_fd[r]);
    if (maxfix == 0) return;                          // all rows reset at step 0
#pragma unroll
    for (int r = 0; r < 4; r++) {
        rbr[r] = rowbits[rowg * 4 + r];
        fdr[r] = sh_fd[rowg * 4 + r];
    }

    // carry-in: speculative end of chunk c-1, with chunk-c step-0 reset
    {
        short8 hv = *(const short8*)(hend + ((size_t)(c - 1) * 256 + b0 + hrow) * 256 + hcol);
        if (rowbits[hrow] & 1u) { short8 z = {0,0,0,0,0,0,0,0}; hv = z; }
        *(short8*)&hT[0][hrow][hcol] = hv;
    }
    __syncthreads();

    const size_t gstep = (size_t)16 * 512 * 8;
    const size_t gb0 = ((size_t)(t0 * 16 + g) * 512 + tid) * 8;

    int cur = 0;
    for (int tp = 0; tp < maxfix; tp++) {
        const int nxt = cur ^ 1;

        f32x4 acc0 = 0, acc1 = 0, acc2 = 0, acc3 = 0, acc4 = 0, acc5 = 0;
#pragma unroll
        for (int ks = 0; ks < 8; ks++) {
            short8 a = *(const short8*)&hT[cur][lc][ks * 32 + rowg * 8];
            acc0 = __builtin_amdgcn_mfma_f32_16x16x32_bf16(a, Bf[0][ks], acc0, 0, 0, 0);
            acc1 = __builtin_amdgcn_mfma_f32_16x16x32_bf16(a, Bf[1][ks], acc1, 0, 0, 0);
            acc2 = __builtin_amdgcn_mfma_f32_16x16x32_bf16(a, Bf[2][ks], acc2, 0, 0, 0);
            acc3 = __builtin_amdgcn_mfma_f32_16x16x32_bf16(a, Bf[3][ks], acc3, 0, 0, 0);
            acc4 = __builtin_amdgcn_mfma_f32_16x16x32_bf16(a, Bf[4][ks], acc4, 0, 0, 0);
            acc5 = __builtin_amdgcn_mfma_f32_16x16x32_bf16(a, Bf[5][ks], acc5, 0, 0, 0);
        }

        size_t gb = gb0 + (size_t)tp * gstep;
        short8 vir = *(const short8*)(gi + gb);
        short8 viz = *(const short8*)(gi + GIPL + gb);
        short8 vin = *(const short8*)(gi + 2 * GIPL + gb);

        unsigned short* yb = y + (size_t)((t0 + tp) * 256 + b0) * 256;
#pragma unroll
        for (int s = 0; s < 2; s++) {
            const int j = w * 32 + s * 16 + lc;
            f32x4 hrv = s ? acc1 : acc0;
            f32x4 hzv = s ? acc3 : acc2;
            f32x4 hnv = s ? acc5 : acc4;
            float bh = s ? bh1 : bh0;
#pragma unroll
            for (int r = 0; r < 4; r++) {
                int row = rowg * 4 + r;
                float ir  = bf2f((unsigned short)vir[r * 2 + s]);
                float iz  = bf2f((unsigned short)viz[r * 2 + s]);
                float inn = bf2f((unsigned short)vin[r * 2 + s]);
                float ho  = bf2f(hT[cur][row][j]);
                unsigned short hb = gru_cell(ir, iz, inn, ho, hrv[r], hzv[r], hnv[r], bh);
                if (tp < fdr[r]) yb[row * 256 + j] = hb;   // only fix wrong prefix
                unsigned short hw = hb;
                if (tp + 1 < CHUNK && ((rbr[r] >> (tp + 1)) & 1u)) hw = 0;
                hT[nxt][row][j] = hw;
            }
        }
        __syncthreads();
        cur = nxt;
    }
}

// ---------------------------------------------------------------------------
// GRU fixup FALLBACK (sequential over chunks): only runs if flag was set.
// ---------------------------------------------------------------------------
__global__ __launch_bounds__(512, 1) void k_gru_fix(
    const unsigned short* __restrict__ gi, const unsigned short* __restrict__ WhF,
    const int* __restrict__ dones, const float* __restrict__ bhn,
    const unsigned short* __restrict__ hend, unsigned short* __restrict__ y,
    const int* __restrict__ flag)
{
    if (*flag == 0) return;                   // uniform: common case, exit fast

    __shared__ unsigned short hT[2][16][264];
    __shared__ unsigned int rowbits[16];
    __shared__ int sh_fd[16];
    const int tid = threadIdx.x, w = tid >> 6, L = tid & 63;
    const int b0 = blockIdx.x * 16, g = blockIdx.x;
    const int rowg = L >> 4, lc = L & 15;
    const int hrow = tid >> 5, hcol = (tid & 31) * 8;

    short8 Bf[6][8];
#pragma unroll
    for (int i6 = 0; i6 < 6; i6++)
#pragma unroll
        for (int ks = 0; ks < 8; ks++)
            Bf[i6][ks] = *(const short8*)(WhF + ((((size_t)w * 6 + i6) * 8 + ks) * 64 + L) * 8);

    const float bh0 = bhn[w * 32 + lc], bh1 = bhn[w * 32 + 16 + lc];

    // carry = corrected end of chunk 0 (chunk 0 speculation used true h0)
    *(short8*)&hT[0][hrow][hcol] =
        *(const short8*)(hend + (size_t)(b0 + hrow) * 256 + hcol);
    int cur = 0;

    const size_t gstep = (size_t)16 * 512 * 8;

    for (int c = 1; c < NCH; c++) {
        const int t0 = c * CHUNK;
        if (tid < 16) rowbits[tid] = 0;
        __syncthreads();
        {
            int tp = tid >> 4, r = tid & 15;
            if (dones[(t0 + tp) * 256 + b0 + r]) atomicOr(&rowbits[r], 1u << tp);
        }
        __syncthreads();
        if (tid < 16) {
            unsigned m = rowbits[tid];
            sh_fd[tid] = m ? __builtin_ctz(m) : CHUNK;
        }
        __syncthreads();

        int maxfix = 0;
        unsigned rbr[4]; int fdr[4];
#pragma unroll
        for (int r = 0; r < 16; r++) maxfix = max(maxfix, sh_fd[r]);
#pragma unroll
        for (int r = 0; r < 4; r++) {
            rbr[r] = rowbits[rowg * 4 + r];
            fdr[r] = sh_fd[rowg * 4 + r];
        }
        // apply this chunk's step-0 reset to the carry
        if (rowbits[hrow] & 1u) {
#pragma unroll
            for (int cc = 0; cc < 8; cc++) hT[cur][hrow][hcol + cc] = 0;
        }
        __syncthreads();

        const size_t gb0 = ((size_t)(t0 * 16 + g) * 512 + tid) * 8;

        for (int tp = 0; tp < maxfix; tp++) {
            const int nxt = cur ^ 1;

            f32x4 acc0 = 0, acc1 = 0, acc2 = 0, acc3 = 0, acc4 = 0, acc5 = 0;
#pragma unroll
            for (int ks = 0; ks < 8; ks++) {
                short8 a = *(const short8*)&hT[cur][lc][ks * 32 + rowg * 8];
                acc0 = __builtin_amdgcn_mfma_f32_16x16x32_bf16(a, Bf[0][ks], acc0, 0, 0, 0);
                acc1 = __builtin_amdgcn_mfma_f32_16x16x32_bf16(a, Bf[1][ks], acc1, 0, 0, 0);
                acc2 = __builtin_amdgcn_mfma_f32_16x16x32_bf16(a, Bf[2][ks], acc2, 0, 0, 0);
                acc3 = __builtin_amdgcn_mfma_f32_16x16x32_bf16(a, Bf[3][ks], acc3, 0, 0, 0);
                acc4 = __builtin_amdgcn_mfma_f32_16x16x32_bf16(a, Bf[4][ks], acc4, 0, 0, 0);
                acc5 = __builtin_amdgcn_mfma_f32_16x16x32_bf16(a, Bf[5][ks], acc5, 0, 0, 0);
            }

            size_t gb = gb0 + (size_t)tp * gstep;
            short8 vir = *(const short8*)(gi + gb);
            short8 viz = *(const short8*)(gi + GIPL + gb);
            short8 vin = *(const short8*)(gi + 2 * GIPL + gb);

            unsigned short* yb = y + (size_t)((t0 + tp) * 256 + b0) * 256;
#pragma unroll
            for (int s = 0; s < 2; s++) {
                const int j = w * 32 + s * 16 + lc;
                f32x4 hrv = s ? acc1 : acc0;
                f32x4 hzv = s ? acc3 : acc2;
                f32x4 hnv = s ? acc5 : acc4;
                float bh = s ? bh1 : bh0;
#pragma unroll
                for (int r = 0; r < 4; r++) {
                    int row = rowg * 4 + r;
                    float ir  = bf2f((unsigned short)vir[r * 2 + s]);
                    float iz  = bf2f((unsigned short)viz[r * 2 + s]);
                    float inn = bf2f((unsigned short)vin[r * 2 + s]);
                    float ho  = bf2f(hT[cur][row][j]);
                    unsigned short hb = gru_cell(ir, iz, inn, ho, hrv[r], hzv[r], hnv[r], bh);
                    if (tp < fdr[r]) yb[row * 256 + j] = hb;   // only fix wrong prefix
                    unsigned short hw = hb;
                    if (tp + 1 < CHUNK && ((rbr[r] >> (tp + 1)) & 1u)) hw = 0;
                    hT[nxt][row][j] = hw;
                }
            }
            __syncthreads();
            cur = nxt;
        }

        // splice: rows that saw a done have correct speculative h_end
        if (sh_fd[hrow] < CHUNK) {
            *(short8*)&hT[cur][hrow][hcol] =
                *(const short8*)(hend + ((size_t)c * 256 + b0 + hrow) * 256 + hcol);
        }
        __syncthreads();
    }
}

// ---------------------------------------------------------------------------
// G4: logits (unchanged)
// ---------------------------------------------------------------------------
__global__ __launch_bounds__(256, 2) void k_logits(
    const unsigned short* __restrict__ ac, const unsigned short* __restrict__ Bt,
    const float* __restrict__ blog,
    const int* __restrict__ av1, const int* __restrict__ av2,
    const int* __restrict__ av3, const int* __restrict__ av4,
    float* __restrict__ outp)
{
    __shared__ unsigned short As[128][72];
    __shared__ unsigned short Bs[160][72];
    const int tid = threadIdx.x, w = tid >> 6, L = tid & 63;
    const int m0 = blockIdx.x * 128;
    const int sr = tid >> 1, sh = (tid & 1) * 32;
    const int lc = L & 15, lq8 = (L >> 4) * 8, lr = (L >> 4) * 4;

    f32x4 acc[2][10];
#pragma unroll
    for (int i = 0; i < 2; i++)
#pragma unroll
        for (int j = 0; j < 10; j++) acc[i][j] = 0;

    const unsigned short* Ag = ac + (size_t)(m0 + sr) * 512 + sh;

    for (int kt = 0; kt < 256; kt += 64) {
#pragma unroll
        for (int c = 0; c < 32; c += 8)
            *(short8*)&As[sr][sh + c] = *(const short8*)(Ag + kt + c);
        for (int u = tid; u < 320; u += 256) {
            int br = u >> 1, bh2 = (u & 1) * 32;
#pragma unroll
            for (int c = 0; c < 32; c += 8)
                *(short8*)&Bs[br][bh2 + c] = *(const short8*)(Bt + (size_t)br * 256 + kt + bh2 + c);
        }
        __syncthreads();
#pragma unroll
        for (int ks = 0; ks < 2; ks++) {
            short8 a[2], b[10];
#pragma unroll
            for (int i = 0; i < 2; i++)
                a[i] = *(const short8*)&As[w * 32 + i * 16 + lc][ks * 32 + lq8];
#pragma unroll
            for (int j = 0; j < 10; j++)
                b[j] = *(const short8*)&Bs[j * 16 + lc][ks * 32 + lq8];
#pragma unroll
            for (int i = 0; i < 2; i++)
#pragma unroll
                for (int j = 0; j < 10; j++)
                    acc[i][j] = __builtin_amdgcn_mfma_f32_16x16x32_bf16(a[i], b[j], acc[i][j], 0, 0, 0);
        }
        __syncthreads();
    }
#pragma unroll
    for (int j = 0; j < 10; j++) {
        int col = j * 16 + lc;
        if (col >= 144) continue;
        int gbase, adim; const int* av; size_t obase;
        if      (col < 32) { gbase = 0;  adim = 32; av = av1; obase = OUT_LC1; }
        else if (col < 64) { gbase = 32; adim = 32; av = av2; obase = OUT_LC2; }
        else if (col < 80) { gbase = 64; adim = 16; av = av3; obase = OUT_MC;  }
        else               { gbase = 80; adim = 64; av = av4; obase = OUT_HINT;}
        int cof = col - gbase;
        float bv = blog[col];
#pragma unroll
        for (int i = 0; i < 2; i++)
#pragma unroll
            for (int rg = 0; rg < 4; rg++) {
                int R = m0 + w * 32 + i * 16 + lr + rg;
                float v = acc[i][j][rg] + bv;
                int a_ = av[(size_t)R * adim + cof];
                v -= (1.f - (float)a_) * 1e10f;
                outp[obase + (size_t)R * adim + cof] = v;
            }
    }
}

// ---------------------------------------------------------------------------
// G5: critic (unchanged)
// ---------------------------------------------------------------------------
__global__ __launch_bounds__(256, 4) void k_critic(
    const unsigned short* __restrict__ ac, const float* __restrict__ W_c2,
    const float* __restrict__ b_c2, float* __restrict__ outp)
{
    const int tid = threadIdx.x, w = tid >> 6, L = tid & 63;
    f32x4 wv = *(const f32x4*)(W_c2 + L * 4);
    float bb = b_c2[0];
    int base = blockIdx.x * 64 + w * 16;
    for (int rr = 0; rr < 16; rr++) {
        int R = base + rr;
        const unsigned short* p = ac + (size_t)R * 512 + 256 + L * 4;
        float s = bf2f(p[0]) * wv[0] + bf2f(p[1]) * wv[1] +
                  bf2f(p[2]) * wv[2] + bf2f(p[3]) * wv[3];
#pragma unroll
        for (int o = 32; o > 0; o >>= 1) s += __shfl_down(s, o);
        if (L == 0) outp[OUT_CRIT + R] = s + bb;
    }
}

__global__ __launch_bounds__(256, 4) void k_hidden(
    const unsigned short* __restrict__ y, float* __restrict__ outp)
{
    int i = blockIdx.x * 256 + threadIdx.x;
    outp[OUT_HID + i] = bf2f(y[(size_t)511 * 65536 + i]);
}

// ---------------------------------------------------------------------------
extern "C" void kernel_launch(void* const* d_in, const int* in_sizes, int n_in,
                              void* d_out, int out_size, void* d_ws, size_t ws_size,
                              hipStream_t stream)
{
    const float* hidden = (const float*)d_in[0];
    const float* obs    = (const float*)d_in[1];
    const int*   dones  = (const int*)d_in[2];
    const int*   av1    = (const int*)d_in[3];
    const int*   av2    = (const int*)d_in[4];
    const int*   av3    = (const int*)d_in[5];
    const int*   av4    = (const int*)d_in[6];
    const float* W_emb  = (const float*)d_in[7];
    const float* b_emb  = (const float*)d_in[8];
    const float* Wi     = (const float*)d_in[9];
    const float* bi     = (const float*)d_in[10];
    const float* Wh     = (const float*)d_in[11];
    const float* bhn    = (const float*)d_in[12];
    const float* W_a    = (const float*)d_in[13];
    const float* b_a    = (const float*)d_in[14];
    const float* W_lc1  = (const float*)d_in[15];
    const float* b_lc1  = (const float*)d_in[16];
    const float* W_lc2  = (const float*)d_in[17];
    const float* b_lc2  = (const float*)d_in[18];
    const float* W_mc   = (const float*)d_in[19];
    const float* b_mc   = (const float*)d_in[20];
    const float* W_hint = (const float*)d_in[21];
    const float* b_hint = (const float*)d_in[22];
    const float* W_c1   = (const float*)d_in[23];
    const float* b_c1   = (const float*)d_in[24];
    const float* W_c2   = (const float*)d_in[25];
    const float* b_c2   = (const float*)d_in[26];

    char* ws = (char*)d_ws;
    unsigned short* WembT = (unsigned short*)(ws + 0);
    unsigned short* WiT   = (unsigned short*)(ws + 262144);
    unsigned short* WhF   = (unsigned short*)(ws + 655360);
    unsigned short* WacT  = (unsigned short*)(ws + 1048576);
    unsigned short* WlogT = (unsigned short*)(ws + 1310720);
    float*          blog  = (float*)(ws + 1392640);
    int*            fflag = (int*)(ws + 1393280);
    // hend (2 MB) / ac (134 MB) share a region (emb no longer exists:
    // it lives in LDS inside k_fused_g12). hend lives gru_main->gru_fix;
    // ac written by G3 after fixup.
    unsigned short* hend  = (unsigned short*)(ws + 1393664);
    unsigned short* ac    = hend;
    unsigned short* gibuf = (unsigned short*)(ws + 135611392);
    unsigned short* ybuf  = (unsigned short*)(ws + 336937984);
    float* outp = (float*)d_out;

    k_prep<<<2721, 256, 0, stream>>>(W_emb, Wi, Wh, W_a, W_c1, W_lc1, W_lc2,
                                     W_mc, W_hint, b_lc1, b_lc2, b_mc, b_hint,
                                     WembT, WiT, WhF, WacT, WlogT, blog, fflag);
    k_fused_g12<<<2048, 512, 0, stream>>>(obs, WembT, b_emb, WiT, bi, gibuf);
    k_gru_main<<<256, 512, 0, stream>>>(gibuf, WhF, dones, hidden, bhn, ybuf, hend);
    k_gru_fix_par<<<240, 512, 0, stream>>>(gibuf, WhF, dones, bhn, hend, ybuf, fflag);
    k_gru_fix<<<16, 512, 0, stream>>>(gibuf, WhF, dones, bhn, hend, ybuf, fflag);
    k_gemm_ac<<<2048, 512, 0, stream>>>(ybuf, WacT, b_a, b_c1, ac);
    k_logits<<<1024, 256, 0, stream>>>(ac, WlogT, blog, av1, av2, av3, av4, outp);
    k_critic<<<2048, 256, 0, stream>>>(ac, W_c2, b_c2, outp);
    k_hidden<<<2048 / 8, 256, 0, stream>>>(ybuf, outp);
}